// Round 1
// baseline (964.111 us; speedup 1.0000x reference)
//
#include <hip/hip_runtime.h>
#include <math.h>

#define NN 50000
#define EE 800000
#define ETOT (EE + NN)
#define HC 256
#define HEADS 4
#define HID 64
#define OUTD 32
#define NB1 196   // ceil(NN/256)

// ---------------- utility ----------------
__device__ __forceinline__ float wred_sum(float v) {
#pragma unroll
  for (int off = 32; off; off >>= 1) v += __shfl_xor(v, off);
  return v;
}
__device__ __forceinline__ float wred_max(float v) {
#pragma unroll
  for (int off = 32; off; off >>= 1) v = fmaxf(v, __shfl_xor(v, off));
  return v;
}
__device__ __forceinline__ float lrelu(float x) { return x >= 0.f ? x : 0.2f * x; }

__global__ void zero_i32(int* __restrict__ p, int n) {
  int i = blockIdx.x * blockDim.x + threadIdx.x;
  if (i < n) p[i] = 0;
}

// ---------------- CSR build ----------------
__global__ void hist_k(const int* __restrict__ ei, int* __restrict__ cnt) {
  int e = blockIdx.x * blockDim.x + threadIdx.x;
  if (e >= ETOT) return;
  int d = (e < EE) ? ei[EE + e] : (e - EE);
  atomicAdd(&cnt[d], 1);
}

__global__ void scan1_k(const int* __restrict__ cnt, int* __restrict__ part,
                        int* __restrict__ bsum) {
  __shared__ int s[256];
  int t = threadIdx.x, i = blockIdx.x * 256 + t;
  int v = (i < NN) ? cnt[i] : 0;
  s[t] = v;
  __syncthreads();
#pragma unroll
  for (int off = 1; off < 256; off <<= 1) {
    int u = (t >= off) ? s[t - off] : 0;
    __syncthreads();
    s[t] += u;
    __syncthreads();
  }
  if (i < NN) part[i] = s[t] - v;  // exclusive within block
  if (t == 255) bsum[blockIdx.x] = s[255];
}

__global__ void scan2_k(const int* __restrict__ bsum, int* __restrict__ bscan) {
  __shared__ int s[256];
  int t = threadIdx.x;
  int v = (t < NB1) ? bsum[t] : 0;
  s[t] = v;
  __syncthreads();
#pragma unroll
  for (int off = 1; off < 256; off <<= 1) {
    int u = (t >= off) ? s[t - off] : 0;
    __syncthreads();
    s[t] += u;
    __syncthreads();
  }
  if (t < NB1) bscan[t] = s[t] - v;
}

__global__ void scan3_k(const int* __restrict__ part, const int* __restrict__ bscan,
                        int* __restrict__ offs, int* __restrict__ cursor) {
  int i = blockIdx.x * 256 + threadIdx.x;
  if (i < NN) {
    int v = part[i] + bscan[blockIdx.x];
    offs[i] = v;
    cursor[i] = v;
  }
  if (i == 0) offs[NN] = ETOT;
}

__global__ void scatter_k(const int* __restrict__ ei, int* __restrict__ cursor,
                          int* __restrict__ elist) {
  int e = blockIdx.x * blockDim.x + threadIdx.x;
  if (e >= ETOT) return;
  int s, d;
  if (e < EE) { s = ei[e]; d = ei[EE + e]; } else { s = d = e - EE; }
  int pos = atomicAdd(&cursor[d], 1);
  elist[pos] = s;
}

// ---------------- layer 1: h = x @ W1, fused e_src/e_dst ----------------
__global__ __launch_bounds__(256) void l1_h_k(
    const float* __restrict__ x, const float* __restrict__ W1,
    const float* __restrict__ asf, const float* __restrict__ adf,
    float* __restrict__ h, float* __restrict__ es, float* __restrict__ ed) {
  int t = threadIdx.x, w = t >> 6;
  float wc[7];
#pragma unroll
  for (int k = 0; k < 7; ++k) wc[k] = W1[k * HC + t];
  float av = asf[t], dv = adf[t];
  for (int i = blockIdx.x; i < NN; i += gridDim.x) {
    float acc = 0.f;
#pragma unroll
    for (int k = 0; k < 7; ++k) acc = fmaf(x[i * 7 + k], wc[k], acc);
    h[(size_t)i * HC + t] = acc;
    float a = wred_sum(acc * av);
    float d = wred_sum(acc * dv);
    if ((t & 63) == 0) { es[i * HEADS + w] = a; ed[i * HEADS + w] = d; }
  }
}

// ---------------- GAT aggregate, heads=4, ch=64 ----------------
__global__ __launch_bounds__(256) void gat_agg256(
    const float* __restrict__ h, const float* __restrict__ es,
    const float* __restrict__ ed, const int* __restrict__ offs,
    const int* __restrict__ elist, const float* __restrict__ bias,
    float* __restrict__ out) {
  int t = threadIdx.x, w = t >> 6, lane = t & 63;
  float bv = bias[t];
  for (int i = blockIdx.x; i < NN; i += gridDim.x) {
    int base = offs[i], end = offs[i + 1];
    float edv = ed[i * HEADS + w];
    float m = -1e30f;
    for (int e = base + lane; e < end; e += 64) {
      float s = lrelu(es[elist[e] * HEADS + w] + edv);
      m = fmaxf(m, s);
    }
    m = wred_max(m);
    float denom = 0.f, acc = 0.f;
    for (int e = base; e < end; ++e) {
      int src = elist[e];
      float s = lrelu(es[src * HEADS + w] + edv);
      float ex = __expf(s - m);
      denom += ex;
      acc = fmaf(ex, h[(size_t)src * HC + (w << 6) + lane], acc);
    }
    out[(size_t)i * HC + t] = acc / (denom + 1e-16f) + bv;
  }
}

// ---------------- BatchNorm ----------------
__global__ __launch_bounds__(256) void bn_stats_k(const float* __restrict__ X,
                                                  float* __restrict__ sums) {
  int t = threadIdx.x;
  int r0 = blockIdx.x * 64;
  int rend = min(r0 + 64, NN);
  float s = 0.f, q = 0.f;
  for (int r = r0; r < rend; ++r) {
    float v = X[(size_t)r * HC + t];
    s += v;
    q = fmaf(v, v, q);
  }
  atomicAdd(&sums[t], s);
  atomicAdd(&sums[HC + t], q);
}

__global__ void bn_final_k(const float* __restrict__ sums, const float* __restrict__ g,
                           const float* __restrict__ be, float* __restrict__ ab) {
  int t = threadIdx.x;
  float mu = sums[t] * (1.f / NN);
  float var = sums[HC + t] * (1.f / NN) - mu * mu;
  float a = g[t] * rsqrtf(var + 1e-5f);
  ab[t] = a;
  ab[HC + t] = fmaf(-mu, a, be[t]);
}

__global__ __launch_bounds__(256) void bn_apply_relu_k(float* __restrict__ X,
                                                       const float* __restrict__ ab) {
  const int total = NN * (HC / 4);
  for (int i = blockIdx.x * blockDim.x + threadIdx.x; i < total;
       i += gridDim.x * blockDim.x) {
    float4 v = ((float4*)X)[i];
    int cb = (i & 63) * 4;
    v.x = fmaxf(fmaf(v.x, ab[cb + 0], ab[HC + cb + 0]), 0.f);
    v.y = fmaxf(fmaf(v.y, ab[cb + 1], ab[HC + cb + 1]), 0.f);
    v.z = fmaxf(fmaf(v.z, ab[cb + 2], ab[HC + cb + 2]), 0.f);
    v.w = fmaxf(fmaf(v.w, ab[cb + 3], ab[HC + cb + 3]), 0.f);
    ((float4*)X)[i] = v;
  }
}

// ---------------- tiled fp32 GEMM: C[M,256] = A[M,256] @ B[256,256] ----------------
__global__ __launch_bounds__(256) void gemm_tiled(const float* __restrict__ A,
                                                  const float* __restrict__ Bw,
                                                  float* __restrict__ C) {
  __shared__ float As[16][64];
  __shared__ float Bs[16][64];
  const int M = NN, K = HC, Nn = HC;
  int m0 = blockIdx.x * 64, n0 = blockIdx.y * 64;
  int t = threadIdx.x;
  int tx = t & 15, ty = t >> 4;
  float acc[4][4] = {};
  for (int k0 = 0; k0 < K; k0 += 16) {
    {
      int m = t >> 2;
      int kq = (t & 3) * 4;
      int row = m0 + m;
      float4 v = (row < M) ? *(const float4*)&A[(size_t)row * K + k0 + kq]
                           : make_float4(0.f, 0.f, 0.f, 0.f);
      As[kq + 0][m] = v.x;
      As[kq + 1][m] = v.y;
      As[kq + 2][m] = v.z;
      As[kq + 3][m] = v.w;
    }
    {
      int k = t >> 4;
      int nq = (t & 15) * 4;
      float4 v = *(const float4*)&Bw[(size_t)(k0 + k) * Nn + n0 + nq];
      *(float4*)&Bs[k][nq] = v;
    }
    __syncthreads();
#pragma unroll
    for (int k = 0; k < 16; ++k) {
      float4 a4 = *(float4*)&As[k][tx * 4];
      float4 b4 = *(float4*)&Bs[k][ty * 4];
      float av[4] = {a4.x, a4.y, a4.z, a4.w};
      float bv[4] = {b4.x, b4.y, b4.z, b4.w};
#pragma unroll
      for (int i = 0; i < 4; ++i)
#pragma unroll
        for (int j = 0; j < 4; ++j) acc[i][j] = fmaf(av[i], bv[j], acc[i][j]);
    }
    __syncthreads();
  }
#pragma unroll
  for (int i = 0; i < 4; ++i) {
    int row = m0 + tx * 4 + i;
    if (row < M) {
      float4 v = make_float4(acc[i][0], acc[i][1], acc[i][2], acc[i][3]);
      *(float4*)&C[(size_t)row * Nn + n0 + ty * 4] = v;
    }
  }
}

// ---------------- e_src/e_dst for layer 2 ----------------
__global__ __launch_bounds__(256) void esed_k(const float* __restrict__ h,
                                              const float* __restrict__ asf,
                                              const float* __restrict__ adf,
                                              float* __restrict__ es,
                                              float* __restrict__ ed) {
  int t = threadIdx.x, w = t >> 6;
  float av = asf[t], dv = adf[t];
  for (int i = blockIdx.x; i < NN; i += gridDim.x) {
    float v = h[(size_t)i * HC + t];
    float a = wred_sum(v * av);
    float d = wred_sum(v * dv);
    if ((t & 63) == 0) { es[i * HEADS + w] = a; ed[i * HEADS + w] = d; }
  }
}

// ---------------- layer 3: h3 = X @ W3 (256x32), fused e ----------------
__global__ __launch_bounds__(256) void l3_h_k(
    const float* __restrict__ X, const float* __restrict__ W3,
    const float* __restrict__ asf, const float* __restrict__ adf,
    float* __restrict__ h3, float* __restrict__ es3, float* __restrict__ ed3) {
  int t = threadIdx.x;
  int g = t >> 5, c = t & 31;
  float av = asf[c], dv = adf[c];
  for (int ib = blockIdx.x; ib * 8 < NN; ib += gridDim.x) {
    int node = ib * 8 + g;
    if (node >= NN) continue;
    float acc = 0.f;
    const float4* xr = (const float4*)(X + (size_t)node * HC);
#pragma unroll 4
    for (int k4 = 0; k4 < 64; ++k4) {
      float4 xv = xr[k4];
      int kb = k4 * 4;
      acc = fmaf(xv.x, W3[(kb + 0) * OUTD + c], acc);
      acc = fmaf(xv.y, W3[(kb + 1) * OUTD + c], acc);
      acc = fmaf(xv.z, W3[(kb + 2) * OUTD + c], acc);
      acc = fmaf(xv.w, W3[(kb + 3) * OUTD + c], acc);
    }
    h3[(size_t)node * OUTD + c] = acc;
    float a = acc * av, d = acc * dv;
#pragma unroll
    for (int off = 16; off; off >>= 1) {
      a += __shfl_xor(a, off);
      d += __shfl_xor(d, off);
    }
    if (c == 0) { es3[node] = a; ed3[node] = d; }
  }
}

// ---------------- GAT aggregate, heads=1, ch=32 (2 edges per wave iter) --------
__global__ __launch_bounds__(256) void gat_agg32(
    const float* __restrict__ h3, const float* __restrict__ es3,
    const float* __restrict__ ed3, const int* __restrict__ offs,
    const int* __restrict__ elist, const float* __restrict__ b3,
    float* __restrict__ emb) {
  int t = threadIdx.x;
  int wv = t >> 6, lane = t & 63;
  int eo = lane >> 5, c = lane & 31;
  float bv = b3[c];
  for (int i = blockIdx.x * 4 + wv; i < NN; i += gridDim.x * 4) {
    int base = offs[i], end = offs[i + 1];
    float edv = ed3[i];
    float m = -1e30f;
    for (int e = base + lane; e < end; e += 64) {
      m = fmaxf(m, lrelu(es3[elist[e]] + edv));
    }
    m = wred_max(m);
    float denom = 0.f, acc = 0.f;
    for (int e = base + eo; e < end; e += 2) {
      int src = elist[e];
      float s = lrelu(es3[src] + edv);
      float ex = __expf(s - m);
      denom += ex;
      acc = fmaf(ex, h3[(size_t)src * OUTD + c], acc);
    }
    denom += __shfl_xor(denom, 32);
    acc += __shfl_xor(acc, 32);
    if (eo == 0) emb[(size_t)i * OUTD + c] = acc / (denom + 1e-16f) + bv;
  }
}

// ---------------- final MLP: 64 -> 64 -> 32 -> 1 + sigmoid ----------------
__global__ __launch_bounds__(256) void mlp_k(
    const float* __restrict__ emb, const int* __restrict__ srcnode,
    const float* __restrict__ Wm1, const float* __restrict__ bm1,
    const float* __restrict__ Wm2, const float* __restrict__ bm2,
    const float* __restrict__ Wm3, const float* __restrict__ bm3,
    float* __restrict__ outp) {
  __shared__ float z[4][64];
  __shared__ float u1[4][64];
  __shared__ float u2[4][32];
  int t = threadIdx.x, g = t >> 6, l = t & 63;
  int sn = srcnode[0];
  for (int ib = blockIdx.x; ib * 4 < NN; ib += gridDim.x) {
    int node = ib * 4 + g;
    bool ok = node < NN;
    float zv = 0.f;
    if (ok) zv = (l < 32) ? emb[(size_t)sn * OUTD + l] : emb[(size_t)node * OUTD + (l - 32)];
    z[g][l] = zv;
    __syncthreads();
    float a1 = bm1[l];
#pragma unroll 8
    for (int k = 0; k < 64; ++k) a1 = fmaf(z[g][k], Wm1[k * 64 + l], a1);
    u1[g][l] = fmaxf(a1, 0.f);
    __syncthreads();
    if (l < 32) {
      float a2 = bm2[l];
#pragma unroll 8
      for (int k = 0; k < 64; ++k) a2 = fmaf(u1[g][k], Wm2[k * 32 + l], a2);
      u2[g][l] = fmaxf(a2, 0.f);
    }
    __syncthreads();
    float v = (l < 32) ? u2[g][l] * Wm3[l] : 0.f;
    v = wred_sum(v);
    if (l == 0 && ok) {
      float s = v + bm3[0];
      outp[node] = 1.f / (1.f + __expf(-s));
    }
    __syncthreads();
  }
}

// ---------------- host launcher ----------------
extern "C" void kernel_launch(void* const* d_in, const int* in_sizes, int n_in,
                              void* d_out, int out_size, void* d_ws, size_t ws_size,
                              hipStream_t stream) {
  const float* x   = (const float*)d_in[0];
  const int* eidx  = (const int*)d_in[1];
  const int* srcn  = (const int*)d_in[2];
  const float* W1  = (const float*)d_in[3];
  const float* as1 = (const float*)d_in[4];
  const float* ad1 = (const float*)d_in[5];
  const float* b1  = (const float*)d_in[6];
  const float* g1  = (const float*)d_in[7];
  const float* be1 = (const float*)d_in[8];
  const float* W2  = (const float*)d_in[9];
  const float* as2 = (const float*)d_in[10];
  const float* ad2 = (const float*)d_in[11];
  const float* b2  = (const float*)d_in[12];
  const float* g2  = (const float*)d_in[13];
  const float* be2 = (const float*)d_in[14];
  const float* W3  = (const float*)d_in[15];
  const float* as3 = (const float*)d_in[16];
  const float* ad3 = (const float*)d_in[17];
  const float* b3  = (const float*)d_in[18];
  const float* Wm1 = (const float*)d_in[19];
  const float* bm1 = (const float*)d_in[20];
  const float* Wm2 = (const float*)d_in[21];
  const float* bm2 = (const float*)d_in[22];
  const float* Wm3 = (const float*)d_in[23];
  const float* bm3 = (const float*)d_in[24];
  float* outp = (float*)d_out;

  // workspace carve
  float* fw = (float*)d_ws;
  float* bufA = fw;                       fw += (size_t)NN * HC;   // h of current layer
  float* bufB = fw;                       fw += (size_t)NN * HC;   // aggregated / bn'd
  float* es   = fw;                       fw += (size_t)NN * HEADS;
  float* ed   = fw;                       fw += (size_t)NN * HEADS;
  float* h3   = fw;                       fw += (size_t)NN * OUTD;
  float* emb  = fw;                       fw += (size_t)NN * OUTD;
  float* es3  = fw;                       fw += NN;
  float* ed3  = fw;                       fw += NN;
  float* bnsums = fw;                     fw += 2 * HC;            // sum | sumsq
  float* bnab   = fw;                     fw += 2 * HC;            // A | B
  int* iw = (int*)fw;
  int* offs   = iw;                       iw += NN + 1;
  int* cursor = iw;                       iw += NN;                // also histogram counts
  int* elist  = iw;                       iw += ETOT;
  int* part   = iw;                       iw += NN;
  int* bsum   = iw;                       iw += 256;
  int* bscan  = iw;                       iw += 256;

  const int TB = 256;
  const int gE = (ETOT + TB - 1) / TB;

  // ---- CSR build ----
  zero_i32<<<(NN + TB - 1) / TB, TB, 0, stream>>>(cursor, NN);
  hist_k<<<gE, TB, 0, stream>>>(eidx, cursor);
  scan1_k<<<NB1, TB, 0, stream>>>(cursor, part, bsum);
  scan2_k<<<1, TB, 0, stream>>>(bsum, bscan);
  scan3_k<<<NB1, TB, 0, stream>>>(part, bscan, offs, cursor);
  scatter_k<<<gE, TB, 0, stream>>>(eidx, cursor, elist);

  // ---- layer 1 ----
  l1_h_k<<<2048, TB, 0, stream>>>(x, W1, as1, ad1, bufA, es, ed);
  gat_agg256<<<NN, TB, 0, stream>>>(bufA, es, ed, offs, elist, b1, bufB);
  zero_i32<<<2, TB, 0, stream>>>((int*)bnsums, 2 * HC);
  bn_stats_k<<<(NN + 63) / 64, TB, 0, stream>>>(bufB, bnsums);
  bn_final_k<<<1, TB, 0, stream>>>(bnsums, g1, be1, bnab);
  bn_apply_relu_k<<<2048, TB, 0, stream>>>(bufB, bnab);

  // ---- layer 2 ----
  gemm_tiled<<<dim3((NN + 63) / 64, HC / 64), TB, 0, stream>>>(bufB, W2, bufA);
  esed_k<<<2048, TB, 0, stream>>>(bufA, as2, ad2, es, ed);
  gat_agg256<<<NN, TB, 0, stream>>>(bufA, es, ed, offs, elist, b2, bufB);
  zero_i32<<<2, TB, 0, stream>>>((int*)bnsums, 2 * HC);
  bn_stats_k<<<(NN + 63) / 64, TB, 0, stream>>>(bufB, bnsums);
  bn_final_k<<<1, TB, 0, stream>>>(bnsums, g2, be2, bnab);
  bn_apply_relu_k<<<2048, TB, 0, stream>>>(bufB, bnab);

  // ---- layer 3 ----
  l3_h_k<<<(NN + 7) / 8, TB, 0, stream>>>(bufB, W3, as3, ad3, h3, es3, ed3);
  gat_agg32<<<(NN + 3) / 4, TB, 0, stream>>>(h3, es3, ed3, offs, elist, b3, emb);

  // ---- MLP head ----
  mlp_k<<<(NN + 3) / 4, TB, 0, stream>>>(emb, srcn, Wm1, bm1, Wm2, bm2, Wm3, bm3, outp);
}

// Round 2
// 852.410 us; speedup vs baseline: 1.1310x; 1.1310x over previous
//
#include <hip/hip_runtime.h>
#include <hip/hip_fp16.h>
#include <math.h>

#define NN 50000
#define EE 800000
#define ETOT (EE + NN)
#define HC 256
#define HEADS 4
#define OUTD 32
#define NB1 196   // ceil(NN/256)

// ---------------- utility ----------------
__device__ __forceinline__ float wred_sum(float v) {
#pragma unroll
  for (int off = 32; off; off >>= 1) v += __shfl_xor(v, off);
  return v;
}
__device__ __forceinline__ float lrelu(float x) { return x >= 0.f ? x : 0.2f * x; }

__global__ void zero_i32(int* __restrict__ p, int n) {
  int i = blockIdx.x * blockDim.x + threadIdx.x;
  if (i < n) p[i] = 0;
}

// ---------------- CSR build ----------------
__global__ void hist_k(const int* __restrict__ ei, int* __restrict__ cnt) {
  int e = blockIdx.x * blockDim.x + threadIdx.x;
  if (e >= ETOT) return;
  int d = (e < EE) ? ei[EE + e] : (e - EE);
  atomicAdd(&cnt[d], 1);
}

__global__ void scan1_k(const int* __restrict__ cnt, int* __restrict__ part,
                        int* __restrict__ bsum) {
  __shared__ int s[256];
  int t = threadIdx.x, i = blockIdx.x * 256 + t;
  int v = (i < NN) ? cnt[i] : 0;
  s[t] = v;
  __syncthreads();
#pragma unroll
  for (int off = 1; off < 256; off <<= 1) {
    int u = (t >= off) ? s[t - off] : 0;
    __syncthreads();
    s[t] += u;
    __syncthreads();
  }
  if (i < NN) part[i] = s[t] - v;
  if (t == 255) bsum[blockIdx.x] = s[255];
}

__global__ void scan2_k(const int* __restrict__ bsum, int* __restrict__ bscan) {
  __shared__ int s[256];
  int t = threadIdx.x;
  int v = (t < NB1) ? bsum[t] : 0;
  s[t] = v;
  __syncthreads();
#pragma unroll
  for (int off = 1; off < 256; off <<= 1) {
    int u = (t >= off) ? s[t - off] : 0;
    __syncthreads();
    s[t] += u;
    __syncthreads();
  }
  if (t < NB1) bscan[t] = s[t] - v;
}

__global__ void scan3_k(const int* __restrict__ part, const int* __restrict__ bscan,
                        int* __restrict__ offs, int* __restrict__ cursor) {
  int i = blockIdx.x * 256 + threadIdx.x;
  if (i < NN) {
    int v = part[i] + bscan[blockIdx.x];
    offs[i] = v;
    cursor[i] = v;
  }
  if (i == 0) offs[NN] = ETOT;
}

__global__ void scatter_k(const int* __restrict__ ei, int* __restrict__ cursor,
                          int* __restrict__ elist) {
  int e = blockIdx.x * blockDim.x + threadIdx.x;
  if (e >= ETOT) return;
  int s, d;
  if (e < EE) { s = ei[e]; d = ei[EE + e]; } else { s = d = e - EE; }
  int pos = atomicAdd(&cursor[d], 1);
  elist[pos] = s;
}

// ---------------- layer 1: h = x @ W1 (fp16 out), fused e_src/e_dst ----------------
__global__ __launch_bounds__(256) void l1_h_k(
    const float* __restrict__ x, const float* __restrict__ W1,
    const float* __restrict__ asf, const float* __restrict__ adf,
    __half* __restrict__ hb, float* __restrict__ es, float* __restrict__ ed) {
  int t = threadIdx.x, w = t >> 6;
  float wc[7];
#pragma unroll
  for (int k = 0; k < 7; ++k) wc[k] = W1[k * HC + t];
  float av = asf[t], dv = adf[t];
  for (int i = blockIdx.x; i < NN; i += gridDim.x) {
    float acc = 0.f;
#pragma unroll
    for (int k = 0; k < 7; ++k) acc = fmaf(x[i * 7 + k], wc[k], acc);
    hb[(size_t)i * HC + t] = __float2half(acc);
    float a = wred_sum(acc * av);
    float d = wred_sum(acc * dv);
    if ((t & 63) == 0) { es[i * HEADS + w] = a; ed[i * HEADS + w] = d; }
  }
}

// ---------------- GAT aggregate v2, heads=4, ch=64, fp16 h ----------------
// no segment-max (exp args bounded, softmax ratio invariant)
__global__ __launch_bounds__(256) void gat_agg256(
    const __half* __restrict__ hb, const float* __restrict__ es,
    const float* __restrict__ ed, const int* __restrict__ offs,
    const int* __restrict__ elist, const float* __restrict__ bias,
    float* __restrict__ exbuf, float* __restrict__ out) {
  __shared__ float accs[2][256];
  __shared__ float red4[4][4];
  __shared__ float den[4];
  int t = threadIdx.x, wv = t >> 6, lane = t & 63;
  const float4* es4 = (const float4*)es;
  const float4* ed4 = (const float4*)ed;
  float4* exb4 = (float4*)exbuf;
  float bv = bias[t];
  int par = wv >> 1;              // edge parity this wave handles
  int cb = (wv & 1) * 128;        // channel base (as fp32 channel idx)
  int c2 = cb + lane * 2;         // two consecutive channels
  int hd = c2 >> 6;               // head for both channels
  const __half2* hb2 = (const __half2*)hb;

  for (int i = blockIdx.x; i < NN; i += gridDim.x) {
    int base = offs[i], end = offs[i + 1];
    float4 edv = ed4[i];
    // phase B: edge-parallel exp + denom
    float4 ds = make_float4(0.f, 0.f, 0.f, 0.f);
    for (int e = base + t; e < end; e += 256) {
      int src = elist[e];
      float4 s4 = es4[src];
      float4 ex;
      ex.x = __expf(lrelu(s4.x + edv.x));
      ex.y = __expf(lrelu(s4.y + edv.y));
      ex.z = __expf(lrelu(s4.z + edv.z));
      ex.w = __expf(lrelu(s4.w + edv.w));
      exb4[e] = ex;
      ds.x += ex.x; ds.y += ex.y; ds.z += ex.z; ds.w += ex.w;
    }
    ds.x = wred_sum(ds.x); ds.y = wred_sum(ds.y);
    ds.z = wred_sum(ds.z); ds.w = wred_sum(ds.w);
    if (lane == 0) { red4[wv][0] = ds.x; red4[wv][1] = ds.y; red4[wv][2] = ds.z; red4[wv][3] = ds.w; }
    __syncthreads();
    if (t < 4) den[t] = red4[0][t] + red4[1][t] + red4[2][t] + red4[3][t] + 1e-16f;
    // phase C: gather (pure fma)
    float2 acc = make_float2(0.f, 0.f);
#pragma unroll 2
    for (int e = base + par; e < end; e += 2) {
      int src = elist[e];
      float ex = exbuf[e * 4 + hd];
      float2 hf = __half22float2(hb2[(size_t)src * 128 + (c2 >> 1)]);
      acc.x = fmaf(ex, hf.x, acc.x);
      acc.y = fmaf(ex, hf.y, acc.y);
    }
    accs[par][c2] = acc.x;
    accs[par][c2 + 1] = acc.y;
    __syncthreads();
    // phase D: combine + normalize + bias
    float val = (accs[0][t] + accs[1][t]) / den[t >> 6] + bv;
    out[(size_t)i * HC + t] = val;
    __syncthreads();
  }
}

// ---------------- BatchNorm stats ----------------
__global__ __launch_bounds__(256) void bn_stats_k(const float* __restrict__ X,
                                                  float* __restrict__ sums) {
  int t = threadIdx.x;
  int r0 = blockIdx.x * 64;
  int rend = min(r0 + 64, NN);
  float s = 0.f, q = 0.f;
  for (int r = r0; r < rend; ++r) {
    float v = X[(size_t)r * HC + t];
    s += v;
    q = fmaf(v, v, q);
  }
  atomicAdd(&sums[t], s);
  atomicAdd(&sums[HC + t], q);
}

__global__ void bn_final_k(const float* __restrict__ sums, const float* __restrict__ g,
                           const float* __restrict__ be, float* __restrict__ ab) {
  int t = threadIdx.x;
  float mu = sums[t] * (1.f / NN);
  float var = sums[HC + t] * (1.f / NN) - mu * mu;
  float a = g[t] * rsqrtf(var + 1e-5f);
  ab[t] = a;
  ab[HC + t] = fmaf(-mu, a, be[t]);
}

// ------- fp32 GEMM 128x128 tile, fused BN-affine+ReLU on A, fp16 C out -------
__global__ __launch_bounds__(256) void gemm_bn_k(const float* __restrict__ A,
                                                 const float* __restrict__ Bw,
                                                 const float* __restrict__ ab,
                                                 __half* __restrict__ Ch) {
  __shared__ float As[16][132];
  __shared__ float Bs[16][128];
  __shared__ float abL[512];
  int t = threadIdx.x;
  abL[t] = ab[t];
  abL[256 + t] = ab[256 + t];
  int m0 = blockIdx.x * 128, n0 = blockIdx.y * 128;
  int tx = t & 15, ty = t >> 4;
  float acc[8][8] = {};
  __syncthreads();
  for (int k0 = 0; k0 < HC; k0 += 16) {
#pragma unroll
    for (int qq = 0; qq < 2; ++qq) {
      int q = t + qq * 256;
      int row = q >> 2, kq = (q & 3) * 4;
      int grow = m0 + row;
      float4 v = (grow < NN) ? *(const float4*)&A[(size_t)grow * HC + k0 + kq]
                             : make_float4(0.f, 0.f, 0.f, 0.f);
      v.x = fmaxf(fmaf(v.x, abL[k0 + kq + 0], abL[256 + k0 + kq + 0]), 0.f);
      v.y = fmaxf(fmaf(v.y, abL[k0 + kq + 1], abL[256 + k0 + kq + 1]), 0.f);
      v.z = fmaxf(fmaf(v.z, abL[k0 + kq + 2], abL[256 + k0 + kq + 2]), 0.f);
      v.w = fmaxf(fmaf(v.w, abL[k0 + kq + 3], abL[256 + k0 + kq + 3]), 0.f);
      As[kq + 0][row] = v.x;
      As[kq + 1][row] = v.y;
      As[kq + 2][row] = v.z;
      As[kq + 3][row] = v.w;
    }
#pragma unroll
    for (int qq = 0; qq < 2; ++qq) {
      int q = t + qq * 256;
      int kk = q >> 5, nq = (q & 31) * 4;
      *(float4*)&Bs[kk][nq] = *(const float4*)&Bw[(size_t)(k0 + kk) * HC + n0 + nq];
    }
    __syncthreads();
#pragma unroll
    for (int k = 0; k < 16; ++k) {
      float a8[8], b8[8];
      *(float4*)&a8[0] = *(float4*)&As[k][tx * 8];
      *(float4*)&a8[4] = *(float4*)&As[k][tx * 8 + 4];
      *(float4*)&b8[0] = *(float4*)&Bs[k][ty * 8];
      *(float4*)&b8[4] = *(float4*)&Bs[k][ty * 8 + 4];
#pragma unroll
      for (int i = 0; i < 8; ++i)
#pragma unroll
        for (int j = 0; j < 8; ++j) acc[i][j] = fmaf(a8[i], b8[j], acc[i][j]);
    }
    __syncthreads();
  }
#pragma unroll
  for (int i = 0; i < 8; ++i) {
    int row = m0 + tx * 8 + i;
    if (row < NN) {
      __half h8[8];
#pragma unroll
      for (int j = 0; j < 8; ++j) h8[j] = __float2half(acc[i][j]);
      *(uint4*)&Ch[(size_t)row * HC + n0 + ty * 8] = *(uint4*)h8;
    }
  }
}

// ---------------- e_src/e_dst for layer 2 (fp16 h) ----------------
__global__ __launch_bounds__(256) void esed_k(const __half* __restrict__ hb,
                                              const float* __restrict__ asf,
                                              const float* __restrict__ adf,
                                              float* __restrict__ es,
                                              float* __restrict__ ed) {
  int t = threadIdx.x, w = t >> 6;
  float av = asf[t], dv = adf[t];
  for (int i = blockIdx.x; i < NN; i += gridDim.x) {
    float v = __half2float(hb[(size_t)i * HC + t]);
    float a = wred_sum(v * av);
    float d = wred_sum(v * dv);
    if ((t & 63) == 0) { es[i * HEADS + w] = a; ed[i * HEADS + w] = d; }
  }
}

// ---------------- layer 3: h3 = relu(affine(X)) @ W3, fused e ----------------
__global__ __launch_bounds__(256) void l3_h_k(
    const float* __restrict__ X, const float* __restrict__ ab,
    const float* __restrict__ W3, const float* __restrict__ asf,
    const float* __restrict__ adf, float* __restrict__ h3,
    float* __restrict__ es3, float* __restrict__ ed3) {
  __shared__ float abL[512];
  int t = threadIdx.x;
  abL[t] = ab[t];
  abL[256 + t] = ab[256 + t];
  __syncthreads();
  int g = t >> 5, c = t & 31;
  float av = asf[c], dv = adf[c];
  for (int ib = blockIdx.x; ib * 8 < NN; ib += gridDim.x) {
    int node = ib * 8 + g;
    if (node >= NN) continue;
    float acc = 0.f;
    const float4* xr = (const float4*)(X + (size_t)node * HC);
#pragma unroll 4
    for (int k4 = 0; k4 < 64; ++k4) {
      float4 xv = xr[k4];
      int kb = k4 * 4;
      float x0 = fmaxf(fmaf(xv.x, abL[kb + 0], abL[256 + kb + 0]), 0.f);
      float x1 = fmaxf(fmaf(xv.y, abL[kb + 1], abL[256 + kb + 1]), 0.f);
      float x2 = fmaxf(fmaf(xv.z, abL[kb + 2], abL[256 + kb + 2]), 0.f);
      float x3 = fmaxf(fmaf(xv.w, abL[kb + 3], abL[256 + kb + 3]), 0.f);
      acc = fmaf(x0, W3[(kb + 0) * OUTD + c], acc);
      acc = fmaf(x1, W3[(kb + 1) * OUTD + c], acc);
      acc = fmaf(x2, W3[(kb + 2) * OUTD + c], acc);
      acc = fmaf(x3, W3[(kb + 3) * OUTD + c], acc);
    }
    h3[(size_t)node * OUTD + c] = acc;
    float a = acc * av, d = acc * dv;
#pragma unroll
    for (int off = 16; off; off >>= 1) {
      a += __shfl_xor(a, off);
      d += __shfl_xor(d, off);
    }
    if (c == 0) { es3[node] = a; ed3[node] = d; }
  }
}

// ---------------- GAT aggregate v2, heads=1, ch=32 ----------------
__global__ __launch_bounds__(256) void gat_agg32(
    const float* __restrict__ h3, const float* __restrict__ es3,
    const float* __restrict__ ed3, const int* __restrict__ offs,
    const int* __restrict__ elist, const float* __restrict__ b3,
    float* __restrict__ exbuf, float* __restrict__ emb) {
  __shared__ float accs[8][32];
  __shared__ float red1[4];
  __shared__ float den;
  int t = threadIdx.x, wv = t >> 6, lane = t & 63;
  int way = t >> 5, c = t & 31;
  float bv = b3[c];
  for (int i = blockIdx.x; i < NN; i += gridDim.x) {
    int base = offs[i], end = offs[i + 1];
    float edv = ed3[i];
    float ds = 0.f;
    for (int e = base + t; e < end; e += 256) {
      float ex = __expf(lrelu(es3[elist[e]] + edv));
      exbuf[e] = ex;
      ds += ex;
    }
    ds = wred_sum(ds);
    if (lane == 0) red1[wv] = ds;
    __syncthreads();
    if (t == 0) den = red1[0] + red1[1] + red1[2] + red1[3] + 1e-16f;
    float acc = 0.f;
#pragma unroll 2
    for (int e = base + way; e < end; e += 8) {
      acc = fmaf(exbuf[e], h3[(size_t)elist[e] * OUTD + c], acc);
    }
    accs[way][c] = acc;
    __syncthreads();
    if (t < 32) {
      float s = 0.f;
#pragma unroll
      for (int j = 0; j < 8; ++j) s += accs[j][t];
      emb[(size_t)i * OUTD + t] = s / den + bv;
    }
    __syncthreads();
  }
}

// ---------------- MLP head ----------------
__global__ void c1_k(const float* __restrict__ emb, const int* __restrict__ srcn,
                     const float* __restrict__ Wm1, const float* __restrict__ bm1,
                     float* __restrict__ c1) {
  int l = threadIdx.x;  // 64 threads
  int sn = srcn[0];
  float a = bm1[l];
  for (int k = 0; k < 32; ++k) a = fmaf(emb[(size_t)sn * OUTD + k], Wm1[k * 64 + l], a);
  c1[l] = a;
}

__global__ __launch_bounds__(256) void mlp_k(
    const float* __restrict__ emb, const float* __restrict__ c1,
    const float* __restrict__ Wm1, const float* __restrict__ Wm2,
    const float* __restrict__ bm2, const float* __restrict__ Wm3,
    const float* __restrict__ bm3, float* __restrict__ outp) {
  __shared__ float WL1s[32][64];
  __shared__ float WL2s[64][32];
  __shared__ float W3s[32];
  __shared__ float c1s[64];
  int t = threadIdx.x;
  for (int q = t; q < 2048; q += 256) WL1s[q >> 6][q & 63] = Wm1[(32 + (q >> 6)) * 64 + (q & 63)];
  for (int q = t; q < 2048; q += 256) WL2s[q >> 5][q & 31] = Wm2[q];
  if (t < 32) W3s[t] = Wm3[t];
  if (t < 64) c1s[t] = c1[t];
  __syncthreads();
  int wv = t >> 6, lane = t & 63;
  int p = lane >> 5, c = lane & 31;
  float bm2v = bm2[c];
  float bm3v = bm3[0];
  for (int node = blockIdx.x * 4 + wv; node < NN; node += gridDim.x * 4) {
    float zv = (lane < 32) ? emb[(size_t)node * OUTD + lane] : 0.f;
    float a1 = c1s[lane];
#pragma unroll
    for (int k = 0; k < 32; ++k) a1 = fmaf(__shfl(zv, k), WL1s[k][lane], a1);
    float u1 = fmaxf(a1, 0.f);
    float a2 = 0.f;
#pragma unroll
    for (int j = 0; j < 32; ++j) a2 = fmaf(__shfl(u1, p * 32 + j), WL2s[p * 32 + j][c], a2);
    a2 += __shfl_xor(a2, 32);
    float v = 0.f;
    if (lane < 32) {
      float u2 = fmaxf(a2 + bm2v, 0.f);
      v = u2 * W3s[c];
    }
    v = wred_sum(v);
    if (lane == 0) outp[node] = 1.f / (1.f + __expf(-(v + bm3v)));
  }
}

// ---------------- host launcher ----------------
extern "C" void kernel_launch(void* const* d_in, const int* in_sizes, int n_in,
                              void* d_out, int out_size, void* d_ws, size_t ws_size,
                              hipStream_t stream) {
  const float* x   = (const float*)d_in[0];
  const int* eidx  = (const int*)d_in[1];
  const int* srcn  = (const int*)d_in[2];
  const float* W1  = (const float*)d_in[3];
  const float* as1 = (const float*)d_in[4];
  const float* ad1 = (const float*)d_in[5];
  const float* b1  = (const float*)d_in[6];
  const float* g1  = (const float*)d_in[7];
  const float* be1 = (const float*)d_in[8];
  const float* W2  = (const float*)d_in[9];
  const float* as2 = (const float*)d_in[10];
  const float* ad2 = (const float*)d_in[11];
  const float* b2  = (const float*)d_in[12];
  const float* g2  = (const float*)d_in[13];
  const float* be2 = (const float*)d_in[14];
  const float* W3  = (const float*)d_in[15];
  const float* as3 = (const float*)d_in[16];
  const float* ad3 = (const float*)d_in[17];
  const float* b3  = (const float*)d_in[18];
  const float* Wm1 = (const float*)d_in[19];
  const float* bm1 = (const float*)d_in[20];
  const float* Wm2 = (const float*)d_in[21];
  const float* bm2 = (const float*)d_in[22];
  const float* Wm3 = (const float*)d_in[23];
  const float* bm3 = (const float*)d_in[24];
  float* outp = (float*)d_out;

  // workspace carve (all float counts multiples of 4 -> 16B alignment kept)
  float* fw = (float*)d_ws;
  float* bufB   = fw;  fw += (size_t)NN * HC;        // fp32 agg output
  __half* hbuf  = (__half*)fw; fw += (size_t)NN * HC / 2;  // fp16 h
  float* h3     = fw;  fw += (size_t)NN * OUTD;
  float* emb    = fw;  fw += (size_t)NN * OUTD;
  float* es     = fw;  fw += (size_t)NN * HEADS;
  float* ed     = fw;  fw += (size_t)NN * HEADS;
  float* es3    = fw;  fw += NN;
  float* ed3    = fw;  fw += NN;
  float* bnsums = fw;  fw += 2 * HC;
  float* bnab   = fw;  fw += 2 * HC;
  float* c1     = fw;  fw += 64;
  float* exbuf  = fw;  fw += (size_t)ETOT * 4;
  int* iw = (int*)fw;
  int* offs   = iw;  iw += NN + 1;
  int* cursor = iw;  iw += NN;
  int* elist  = iw;  iw += ETOT;
  int* part   = iw;  iw += NN;
  int* bsum   = iw;  iw += 256;
  int* bscan  = iw;  iw += 256;

  const int TB = 256;
  const int gE = (ETOT + TB - 1) / TB;

  // ---- CSR build ----
  zero_i32<<<(NN + TB - 1) / TB, TB, 0, stream>>>(cursor, NN);
  hist_k<<<gE, TB, 0, stream>>>(eidx, cursor);
  scan1_k<<<NB1, TB, 0, stream>>>(cursor, part, bsum);
  scan2_k<<<1, TB, 0, stream>>>(bsum, bscan);
  scan3_k<<<NB1, TB, 0, stream>>>(part, bscan, offs, cursor);
  scatter_k<<<gE, TB, 0, stream>>>(eidx, cursor, elist);

  // ---- layer 1 ----
  l1_h_k<<<2048, TB, 0, stream>>>(x, W1, as1, ad1, hbuf, es, ed);
  gat_agg256<<<NN, TB, 0, stream>>>(hbuf, es, ed, offs, elist, b1, exbuf, bufB);
  zero_i32<<<2, TB, 0, stream>>>((int*)bnsums, 2 * HC);
  bn_stats_k<<<(NN + 63) / 64, TB, 0, stream>>>(bufB, bnsums);
  bn_final_k<<<1, TB, 0, stream>>>(bnsums, g1, be1, bnab);

  // ---- layer 2 (BN1 affine+relu fused into GEMM A-load) ----
  gemm_bn_k<<<dim3((NN + 127) / 128, HC / 128), TB, 0, stream>>>(bufB, W2, bnab, hbuf);
  esed_k<<<2048, TB, 0, stream>>>(hbuf, as2, ad2, es, ed);
  gat_agg256<<<NN, TB, 0, stream>>>(hbuf, es, ed, offs, elist, b2, exbuf, bufB);
  zero_i32<<<2, TB, 0, stream>>>((int*)bnsums, 2 * HC);
  bn_stats_k<<<(NN + 63) / 64, TB, 0, stream>>>(bufB, bnsums);
  bn_final_k<<<1, TB, 0, stream>>>(bnsums, g2, be2, bnab);

  // ---- layer 3 (BN2 affine+relu fused into l3 X-load) ----
  l3_h_k<<<(NN + 7) / 8, TB, 0, stream>>>(bufB, bnab, W3, as3, ad3, h3, es3, ed3);
  gat_agg32<<<NN, TB, 0, stream>>>(h3, es3, ed3, offs, elist, b3, exbuf, emb);

  // ---- MLP head ----
  c1_k<<<1, 64, 0, stream>>>(emb, srcn, Wm1, bm1, c1);
  mlp_k<<<512, TB, 0, stream>>>(emb, c1, Wm1, Wm2, bm2, Wm3, bm3, outp);
}

// Round 3
// 662.844 us; speedup vs baseline: 1.4545x; 1.2860x over previous
//
#include <hip/hip_runtime.h>
#include <hip/hip_fp16.h>
#include <math.h>

#define NN 50000
#define EE 800000
#define ETOT (EE + NN)
#define HC 256
#define HEADS 4
#define OUTD 32
#define NB1 196   // ceil(NN/256)

// ---------------- utility ----------------
__device__ __forceinline__ float wred_sum(float v) {
#pragma unroll
  for (int off = 32; off; off >>= 1) v += __shfl_xor(v, off);
  return v;
}
__device__ __forceinline__ float lrelu(float x) { return x >= 0.f ? x : 0.2f * x; }

__global__ void zero_i32(int* __restrict__ p, int n) {
  int i = blockIdx.x * blockDim.x + threadIdx.x;
  if (i < n) p[i] = 0;
}

// ---------------- CSR build ----------------
__global__ void hist_k(const int* __restrict__ ei, int* __restrict__ cnt) {
  int e = blockIdx.x * blockDim.x + threadIdx.x;
  if (e >= ETOT) return;
  int d = (e < EE) ? ei[EE + e] : (e - EE);
  atomicAdd(&cnt[d], 1);
}

__global__ void scan1_k(const int* __restrict__ cnt, int* __restrict__ part,
                        int* __restrict__ bsum) {
  __shared__ int s[256];
  int t = threadIdx.x, i = blockIdx.x * 256 + t;
  int v = (i < NN) ? cnt[i] : 0;
  s[t] = v;
  __syncthreads();
#pragma unroll
  for (int off = 1; off < 256; off <<= 1) {
    int u = (t >= off) ? s[t - off] : 0;
    __syncthreads();
    s[t] += u;
    __syncthreads();
  }
  if (i < NN) part[i] = s[t] - v;
  if (t == 255) bsum[blockIdx.x] = s[255];
}

__global__ void scan2_k(const int* __restrict__ bsum, int* __restrict__ bscan) {
  __shared__ int s[256];
  int t = threadIdx.x;
  int v = (t < NB1) ? bsum[t] : 0;
  s[t] = v;
  __syncthreads();
#pragma unroll
  for (int off = 1; off < 256; off <<= 1) {
    int u = (t >= off) ? s[t - off] : 0;
    __syncthreads();
    s[t] += u;
    __syncthreads();
  }
  if (t < NB1) bscan[t] = s[t] - v;
}

__global__ void scan3_k(const int* __restrict__ part, const int* __restrict__ bscan,
                        int* __restrict__ offs, int* __restrict__ cursor) {
  int i = blockIdx.x * 256 + threadIdx.x;
  if (i < NN) {
    int v = part[i] + bscan[blockIdx.x];
    offs[i] = v;
    cursor[i] = v;
  }
  if (i == 0) offs[NN] = ETOT;
}

__global__ void scatter_k(const int* __restrict__ ei, int* __restrict__ cursor,
                          int* __restrict__ elist) {
  int e = blockIdx.x * blockDim.x + threadIdx.x;
  if (e >= ETOT) return;
  int s, d;
  if (e < EE) { s = ei[e]; d = ei[EE + e]; } else { s = d = e - EE; }
  int pos = atomicAdd(&cursor[d], 1);
  elist[pos] = s;
}

// ---------------- layer 1: h = x @ W1 (fp16 out), fused e_src/e_dst ----------------
__global__ __launch_bounds__(256) void l1_h_k(
    const float* __restrict__ x, const float* __restrict__ W1,
    const float* __restrict__ asf, const float* __restrict__ adf,
    __half* __restrict__ hb, float* __restrict__ es, float* __restrict__ ed) {
  int t = threadIdx.x, w = t >> 6;
  float wc[7];
#pragma unroll
  for (int k = 0; k < 7; ++k) wc[k] = W1[k * HC + t];
  float av = asf[t], dv = adf[t];
  for (int i = blockIdx.x; i < NN; i += gridDim.x) {
    float acc = 0.f;
#pragma unroll
    for (int k = 0; k < 7; ++k) acc = fmaf(x[i * 7 + k], wc[k], acc);
    hb[(size_t)i * HC + t] = __float2half(acc);
    float a = wred_sum(acc * av);
    float d = wred_sum(acc * dv);
    if ((t & 63) == 0) { es[i * HEADS + w] = a; ed[i * HEADS + w] = d; }
  }
}

// ------- GAT aggregate v3: wave-per-node, fully fused, no LDS/syncs -------
// lane covers 4 channels (64 lanes x 4 = 256); head = lane>>4.
// denom is accumulated redundantly per 16-lane head group -> zero shuffles.
__global__ __launch_bounds__(256) void gat_agg256(
    const __half* __restrict__ hb, const float* __restrict__ es,
    const float* __restrict__ ed, const int* __restrict__ offs,
    const int* __restrict__ elist, const float* __restrict__ bias,
    float* __restrict__ out) {
  int t = threadIdx.x, wv = t >> 6, lane = t & 63;
  int hd = lane >> 4;
  float4 bv = ((const float4*)bias)[lane];
  const float2* hb4 = (const float2*)hb;  // 8B = 4 halves per lane
  int i = blockIdx.x * 4 + wv;
  if (i >= NN) return;
  int base = offs[i], end = offs[i + 1];
  float edv = ed[i * HEADS + hd];
  float denom = 0.f;
  float4 acc = make_float4(0.f, 0.f, 0.f, 0.f);
#pragma unroll 2
  for (int e = base; e < end; ++e) {
    int src = elist[e];
    float ex = __expf(lrelu(es[src * HEADS + hd] + edv));
    denom += ex;
    float2 raw = hb4[(size_t)src * 64 + lane];
    __half2 p01 = *(__half2*)&raw.x;
    __half2 p23 = *(__half2*)&raw.y;
    float2 h01 = __half22float2(p01);
    float2 h23 = __half22float2(p23);
    acc.x = fmaf(ex, h01.x, acc.x);
    acc.y = fmaf(ex, h01.y, acc.y);
    acc.z = fmaf(ex, h23.x, acc.z);
    acc.w = fmaf(ex, h23.y, acc.w);
  }
  float inv = 1.f / (denom + 1e-16f);
  float4 r;
  r.x = fmaf(acc.x, inv, bv.x);
  r.y = fmaf(acc.y, inv, bv.y);
  r.z = fmaf(acc.z, inv, bv.z);
  r.w = fmaf(acc.w, inv, bv.w);
  ((float4*)(out + (size_t)i * HC))[lane] = r;
}

// ---------------- BatchNorm stats ----------------
__global__ __launch_bounds__(256) void bn_stats_k(const float* __restrict__ X,
                                                  float* __restrict__ sums) {
  int t = threadIdx.x;
  int r0 = blockIdx.x * 64;
  int rend = min(r0 + 64, NN);
  float s = 0.f, q = 0.f;
  for (int r = r0; r < rend; ++r) {
    float v = X[(size_t)r * HC + t];
    s += v;
    q = fmaf(v, v, q);
  }
  atomicAdd(&sums[t], s);
  atomicAdd(&sums[HC + t], q);
}

__global__ void bn_final_k(const float* __restrict__ sums, const float* __restrict__ g,
                           const float* __restrict__ be, float* __restrict__ ab) {
  int t = threadIdx.x;
  float mu = sums[t] * (1.f / NN);
  float var = sums[HC + t] * (1.f / NN) - mu * mu;
  float a = g[t] * rsqrtf(var + 1e-5f);
  ab[t] = a;
  ab[HC + t] = fmaf(-mu, a, be[t]);
}

// ------- fp32 GEMM 128x128 tile, fused BN-affine+ReLU on A, fp16 C out -------
__global__ __launch_bounds__(256) void gemm_bn_k(const float* __restrict__ A,
                                                 const float* __restrict__ Bw,
                                                 const float* __restrict__ ab,
                                                 __half* __restrict__ Ch) {
  __shared__ float As[16][132];
  __shared__ float Bs[16][128];
  __shared__ float abL[512];
  int t = threadIdx.x;
  abL[t] = ab[t];
  abL[256 + t] = ab[256 + t];
  int m0 = blockIdx.x * 128, n0 = blockIdx.y * 128;
  int tx = t & 15, ty = t >> 4;
  float acc[8][8] = {};
  __syncthreads();
  for (int k0 = 0; k0 < HC; k0 += 16) {
#pragma unroll
    for (int qq = 0; qq < 2; ++qq) {
      int q = t + qq * 256;
      int row = q >> 2, kq = (q & 3) * 4;
      int grow = m0 + row;
      float4 v = (grow < NN) ? *(const float4*)&A[(size_t)grow * HC + k0 + kq]
                             : make_float4(0.f, 0.f, 0.f, 0.f);
      v.x = fmaxf(fmaf(v.x, abL[k0 + kq + 0], abL[256 + k0 + kq + 0]), 0.f);
      v.y = fmaxf(fmaf(v.y, abL[k0 + kq + 1], abL[256 + k0 + kq + 1]), 0.f);
      v.z = fmaxf(fmaf(v.z, abL[k0 + kq + 2], abL[256 + k0 + kq + 2]), 0.f);
      v.w = fmaxf(fmaf(v.w, abL[k0 + kq + 3], abL[256 + k0 + kq + 3]), 0.f);
      As[kq + 0][row] = v.x;
      As[kq + 1][row] = v.y;
      As[kq + 2][row] = v.z;
      As[kq + 3][row] = v.w;
    }
#pragma unroll
    for (int qq = 0; qq < 2; ++qq) {
      int q = t + qq * 256;
      int kk = q >> 5, nq = (q & 31) * 4;
      *(float4*)&Bs[kk][nq] = *(const float4*)&Bw[(size_t)(k0 + kk) * HC + n0 + nq];
    }
    __syncthreads();
#pragma unroll
    for (int k = 0; k < 16; ++k) {
      float a8[8], b8[8];
      *(float4*)&a8[0] = *(float4*)&As[k][tx * 8];
      *(float4*)&a8[4] = *(float4*)&As[k][tx * 8 + 4];
      *(float4*)&b8[0] = *(float4*)&Bs[k][ty * 8];
      *(float4*)&b8[4] = *(float4*)&Bs[k][ty * 8 + 4];
#pragma unroll
      for (int i = 0; i < 8; ++i)
#pragma unroll
        for (int j = 0; j < 8; ++j) acc[i][j] = fmaf(a8[i], b8[j], acc[i][j]);
    }
    __syncthreads();
  }
#pragma unroll
  for (int i = 0; i < 8; ++i) {
    int row = m0 + tx * 8 + i;
    if (row < NN) {
      __half h8[8];
#pragma unroll
      for (int j = 0; j < 8; ++j) h8[j] = __float2half(acc[i][j]);
      *(uint4*)&Ch[(size_t)row * HC + n0 + ty * 8] = *(uint4*)h8;
    }
  }
}

// ---------------- e_src/e_dst for layer 2 (fp16 h) ----------------
__global__ __launch_bounds__(256) void esed_k(const __half* __restrict__ hb,
                                              const float* __restrict__ asf,
                                              const float* __restrict__ adf,
                                              float* __restrict__ es,
                                              float* __restrict__ ed) {
  int t = threadIdx.x, w = t >> 6;
  float av = asf[t], dv = adf[t];
  for (int i = blockIdx.x; i < NN; i += gridDim.x) {
    float v = __half2float(hb[(size_t)i * HC + t]);
    float a = wred_sum(v * av);
    float d = wred_sum(v * dv);
    if ((t & 63) == 0) { es[i * HEADS + w] = a; ed[i * HEADS + w] = d; }
  }
}

// ---------------- layer 3: h3 = relu(affine(X)) @ W3, fused e ----------------
__global__ __launch_bounds__(256) void l3_h_k(
    const float* __restrict__ X, const float* __restrict__ ab,
    const float* __restrict__ W3, const float* __restrict__ asf,
    const float* __restrict__ adf, float* __restrict__ h3,
    float* __restrict__ es3, float* __restrict__ ed3) {
  __shared__ float abL[512];
  int t = threadIdx.x;
  abL[t] = ab[t];
  abL[256 + t] = ab[256 + t];
  __syncthreads();
  int g = t >> 5, c = t & 31;
  float av = asf[c], dv = adf[c];
  for (int ib = blockIdx.x; ib * 8 < NN; ib += gridDim.x) {
    int node = ib * 8 + g;
    if (node >= NN) continue;
    float acc = 0.f;
    const float4* xr = (const float4*)(X + (size_t)node * HC);
#pragma unroll 4
    for (int k4 = 0; k4 < 64; ++k4) {
      float4 xv = xr[k4];
      int kb = k4 * 4;
      float x0 = fmaxf(fmaf(xv.x, abL[kb + 0], abL[256 + kb + 0]), 0.f);
      float x1 = fmaxf(fmaf(xv.y, abL[kb + 1], abL[256 + kb + 1]), 0.f);
      float x2 = fmaxf(fmaf(xv.z, abL[kb + 2], abL[256 + kb + 2]), 0.f);
      float x3 = fmaxf(fmaf(xv.w, abL[kb + 3], abL[256 + kb + 3]), 0.f);
      acc = fmaf(x0, W3[(kb + 0) * OUTD + c], acc);
      acc = fmaf(x1, W3[(kb + 1) * OUTD + c], acc);
      acc = fmaf(x2, W3[(kb + 2) * OUTD + c], acc);
      acc = fmaf(x3, W3[(kb + 3) * OUTD + c], acc);
    }
    h3[(size_t)node * OUTD + c] = acc;
    float a = acc * av, d = acc * dv;
#pragma unroll
    for (int off = 16; off; off >>= 1) {
      a += __shfl_xor(a, off);
      d += __shfl_xor(d, off);
    }
    if (c == 0) { es3[node] = a; ed3[node] = d; }
  }
}

// ------- GAT aggregate v3, heads=1, ch=32: wave-per-node, 2 edges/iter -------
__global__ __launch_bounds__(256) void gat_agg32(
    const float* __restrict__ h3, const float* __restrict__ es3,
    const float* __restrict__ ed3, const int* __restrict__ offs,
    const int* __restrict__ elist, const float* __restrict__ b3,
    float* __restrict__ emb) {
  int t = threadIdx.x, wv = t >> 6, lane = t & 63;
  int eo = lane >> 5, c = lane & 31;
  float bv = b3[c];
  int i = blockIdx.x * 4 + wv;
  if (i >= NN) return;
  int base = offs[i], end = offs[i + 1];
  float edv = ed3[i];
  float denom = 0.f, acc = 0.f;
#pragma unroll 2
  for (int e = base + eo; e < end; e += 2) {
    int src = elist[e];
    float ex = __expf(lrelu(es3[src] + edv));
    denom += ex;
    acc = fmaf(ex, h3[(size_t)src * OUTD + c], acc);
  }
  denom += __shfl_xor(denom, 32);
  acc += __shfl_xor(acc, 32);
  if (eo == 0) emb[(size_t)i * OUTD + c] = acc / (denom + 1e-16f) + bv;
}

// ---------------- MLP head ----------------
__global__ void c1_k(const float* __restrict__ emb, const int* __restrict__ srcn,
                     const float* __restrict__ Wm1, const float* __restrict__ bm1,
                     float* __restrict__ c1) {
  int l = threadIdx.x;  // 64 threads
  int sn = srcn[0];
  float a = bm1[l];
  for (int k = 0; k < 32; ++k) a = fmaf(emb[(size_t)sn * OUTD + k], Wm1[k * 64 + l], a);
  c1[l] = a;
}

__global__ __launch_bounds__(256) void mlp_k(
    const float* __restrict__ emb, const float* __restrict__ c1,
    const float* __restrict__ Wm1, const float* __restrict__ Wm2,
    const float* __restrict__ bm2, const float* __restrict__ Wm3,
    const float* __restrict__ bm3, float* __restrict__ outp) {
  __shared__ float WL1s[32][64];
  __shared__ float WL2s[64][32];
  __shared__ float W3s[32];
  __shared__ float c1s[64];
  int t = threadIdx.x;
  for (int q = t; q < 2048; q += 256) WL1s[q >> 6][q & 63] = Wm1[(32 + (q >> 6)) * 64 + (q & 63)];
  for (int q = t; q < 2048; q += 256) WL2s[q >> 5][q & 31] = Wm2[q];
  if (t < 32) W3s[t] = Wm3[t];
  if (t < 64) c1s[t] = c1[t];
  __syncthreads();
  int wv = t >> 6, lane = t & 63;
  int p = lane >> 5, c = lane & 31;
  float bm2v = bm2[c];
  float bm3v = bm3[0];
  for (int node = blockIdx.x * 4 + wv; node < NN; node += gridDim.x * 4) {
    float zv = (lane < 32) ? emb[(size_t)node * OUTD + lane] : 0.f;
    float a1 = c1s[lane];
#pragma unroll
    for (int k = 0; k < 32; ++k) a1 = fmaf(__shfl(zv, k), WL1s[k][lane], a1);
    float u1 = fmaxf(a1, 0.f);
    float a2 = 0.f;
#pragma unroll
    for (int j = 0; j < 32; ++j) a2 = fmaf(__shfl(u1, p * 32 + j), WL2s[p * 32 + j][c], a2);
    a2 += __shfl_xor(a2, 32);
    float v = 0.f;
    if (lane < 32) {
      float u2 = fmaxf(a2 + bm2v, 0.f);
      v = u2 * W3s[c];
    }
    v = wred_sum(v);
    if (lane == 0) outp[node] = 1.f / (1.f + __expf(-(v + bm3v)));
  }
}

// ---------------- host launcher ----------------
extern "C" void kernel_launch(void* const* d_in, const int* in_sizes, int n_in,
                              void* d_out, int out_size, void* d_ws, size_t ws_size,
                              hipStream_t stream) {
  const float* x   = (const float*)d_in[0];
  const int* eidx  = (const int*)d_in[1];
  const int* srcn  = (const int*)d_in[2];
  const float* W1  = (const float*)d_in[3];
  const float* as1 = (const float*)d_in[4];
  const float* ad1 = (const float*)d_in[5];
  const float* b1  = (const float*)d_in[6];
  const float* g1  = (const float*)d_in[7];
  const float* be1 = (const float*)d_in[8];
  const float* W2  = (const float*)d_in[9];
  const float* as2 = (const float*)d_in[10];
  const float* ad2 = (const float*)d_in[11];
  const float* b2  = (const float*)d_in[12];
  const float* g2  = (const float*)d_in[13];
  const float* be2 = (const float*)d_in[14];
  const float* W3  = (const float*)d_in[15];
  const float* as3 = (const float*)d_in[16];
  const float* ad3 = (const float*)d_in[17];
  const float* b3  = (const float*)d_in[18];
  const float* Wm1 = (const float*)d_in[19];
  const float* bm1 = (const float*)d_in[20];
  const float* Wm2 = (const float*)d_in[21];
  const float* bm2 = (const float*)d_in[22];
  const float* Wm3 = (const float*)d_in[23];
  const float* bm3 = (const float*)d_in[24];
  float* outp = (float*)d_out;

  // workspace carve
  float* fw = (float*)d_ws;
  float* bufB   = fw;  fw += (size_t)NN * HC;              // fp32 agg output
  __half* hbuf  = (__half*)fw; fw += (size_t)NN * HC / 2;  // fp16 h
  float* h3     = fw;  fw += (size_t)NN * OUTD;
  float* emb    = fw;  fw += (size_t)NN * OUTD;
  float* es     = fw;  fw += (size_t)NN * HEADS;
  float* ed     = fw;  fw += (size_t)NN * HEADS;
  float* es3    = fw;  fw += NN;
  float* ed3    = fw;  fw += NN;
  float* bnsums = fw;  fw += 2 * HC;
  float* bnab   = fw;  fw += 2 * HC;
  float* c1     = fw;  fw += 64;
  int* iw = (int*)fw;
  int* offs   = iw;  iw += NN + 1;
  int* cursor = iw;  iw += NN;
  int* elist  = iw;  iw += ETOT;
  int* part   = iw;  iw += NN;
  int* bsum   = iw;  iw += 256;
  int* bscan  = iw;  iw += 256;

  const int TB = 256;
  const int gE = (ETOT + TB - 1) / TB;
  const int gN4 = (NN + 3) / 4;

  // ---- CSR build ----
  zero_i32<<<(NN + TB - 1) / TB, TB, 0, stream>>>(cursor, NN);
  hist_k<<<gE, TB, 0, stream>>>(eidx, cursor);
  scan1_k<<<NB1, TB, 0, stream>>>(cursor, part, bsum);
  scan2_k<<<1, TB, 0, stream>>>(bsum, bscan);
  scan3_k<<<NB1, TB, 0, stream>>>(part, bscan, offs, cursor);
  scatter_k<<<gE, TB, 0, stream>>>(eidx, cursor, elist);

  // ---- layer 1 ----
  l1_h_k<<<2048, TB, 0, stream>>>(x, W1, as1, ad1, hbuf, es, ed);
  gat_agg256<<<gN4, TB, 0, stream>>>(hbuf, es, ed, offs, elist, b1, bufB);
  zero_i32<<<2, TB, 0, stream>>>((int*)bnsums, 2 * HC);
  bn_stats_k<<<(NN + 63) / 64, TB, 0, stream>>>(bufB, bnsums);
  bn_final_k<<<1, TB, 0, stream>>>(bnsums, g1, be1, bnab);

  // ---- layer 2 (BN1 affine+relu fused into GEMM A-load) ----
  gemm_bn_k<<<dim3((NN + 127) / 128, HC / 128), TB, 0, stream>>>(bufB, W2, bnab, hbuf);
  esed_k<<<2048, TB, 0, stream>>>(hbuf, as2, ad2, es, ed);
  gat_agg256<<<gN4, TB, 0, stream>>>(hbuf, es, ed, offs, elist, b2, bufB);
  zero_i32<<<2, TB, 0, stream>>>((int*)bnsums, 2 * HC);
  bn_stats_k<<<(NN + 63) / 64, TB, 0, stream>>>(bufB, bnsums);
  bn_final_k<<<1, TB, 0, stream>>>(bnsums, g2, be2, bnab);

  // ---- layer 3 (BN2 affine+relu fused into l3 X-load) ----
  l3_h_k<<<(NN + 7) / 8, TB, 0, stream>>>(bufB, bnab, W3, as3, ad3, h3, es3, ed3);
  gat_agg32<<<gN4, TB, 0, stream>>>(h3, es3, ed3, offs, elist, b3, emb);

  // ---- MLP head ----
  c1_k<<<1, 64, 0, stream>>>(emb, srcn, Wm1, bm1, c1);
  mlp_k<<<512, TB, 0, stream>>>(emb, c1, Wm1, Wm2, bm2, Wm3, bm3, outp);
}

// Round 4
// 589.661 us; speedup vs baseline: 1.6350x; 1.1241x over previous
//
#include <hip/hip_runtime.h>
#include <hip/hip_fp16.h>
#include <math.h>

#define NN 50000
#define EE 800000
#define ETOT (EE + NN)
#define HC 256
#define HEADS 4
#define OUTD 32
#define NB1 196   // ceil(NN/256)

typedef _Float16 f16x8 __attribute__((ext_vector_type(8)));
typedef float f32x4 __attribute__((ext_vector_type(4)));

// ---------------- utility ----------------
__device__ __forceinline__ float wred_sum(float v) {
#pragma unroll
  for (int off = 32; off; off >>= 1) v += __shfl_xor(v, off);
  return v;
}
__device__ __forceinline__ float lrelu(float x) { return x >= 0.f ? x : 0.2f * x; }

__global__ void zero_i32(int* __restrict__ p, int n) {
  int i = blockIdx.x * blockDim.x + threadIdx.x;
  if (i < n) p[i] = 0;
}

// ---------------- CSR build ----------------
__global__ void hist_k(const int* __restrict__ ei, int* __restrict__ cnt) {
  int e = blockIdx.x * blockDim.x + threadIdx.x;
  if (e >= ETOT) return;
  int d = (e < EE) ? ei[EE + e] : (e - EE);
  atomicAdd(&cnt[d], 1);
}

__global__ void scan1_k(const int* __restrict__ cnt, int* __restrict__ part,
                        int* __restrict__ bsum) {
  __shared__ int s[256];
  int t = threadIdx.x, i = blockIdx.x * 256 + t;
  int v = (i < NN) ? cnt[i] : 0;
  s[t] = v;
  __syncthreads();
#pragma unroll
  for (int off = 1; off < 256; off <<= 1) {
    int u = (t >= off) ? s[t - off] : 0;
    __syncthreads();
    s[t] += u;
    __syncthreads();
  }
  if (i < NN) part[i] = s[t] - v;
  if (t == 255) bsum[blockIdx.x] = s[255];
}

__global__ void scan2_k(const int* __restrict__ bsum, int* __restrict__ bscan) {
  __shared__ int s[256];
  int t = threadIdx.x;
  int v = (t < NB1) ? bsum[t] : 0;
  s[t] = v;
  __syncthreads();
#pragma unroll
  for (int off = 1; off < 256; off <<= 1) {
    int u = (t >= off) ? s[t - off] : 0;
    __syncthreads();
    s[t] += u;
    __syncthreads();
  }
  if (t < NB1) bscan[t] = s[t] - v;
}

__global__ void scan3_k(const int* __restrict__ part, const int* __restrict__ bscan,
                        int* __restrict__ offs, int* __restrict__ cursor) {
  int i = blockIdx.x * 256 + threadIdx.x;
  if (i < NN) {
    int v = part[i] + bscan[blockIdx.x];
    offs[i] = v;
    cursor[i] = v;
  }
  if (i == 0) offs[NN] = ETOT;
}

__global__ void scatter_k(const int* __restrict__ ei, int* __restrict__ cursor,
                          int* __restrict__ elist) {
  int e = blockIdx.x * blockDim.x + threadIdx.x;
  if (e >= ETOT) return;
  int s, d;
  if (e < EE) { s = ei[e]; d = ei[EE + e]; } else { s = d = e - EE; }
  int pos = atomicAdd(&cursor[d], 1);
  elist[pos] = s;
}

// ---------------- W2 -> fp16, fragment-ordered for 16x16x32 MFMA B ----------------
// Bh index: frag=(n>>4)*8+(k>>5); lane=(n&15)+16*((k>>3)&3); elem=k&7
__global__ __launch_bounds__(256) void w2_swz_k(const float* __restrict__ W2,
                                                __half* __restrict__ Bh) {
  int idx = blockIdx.x * 256 + threadIdx.x;
  if (idx >= HC * HC) return;
  int k = idx >> 8, n = idx & 255;
  int frag = (n >> 4) * 8 + (k >> 5);
  int lane = (n & 15) + (((k >> 3) & 3) << 4);
  int elem = k & 7;
  Bh[(frag * 64 + lane) * 8 + elem] = __float2half(W2[idx]);
}

// ---------------- layer 1: h = x @ W1 (fp16 out), fused e_src/e_dst ----------------
__global__ __launch_bounds__(256) void l1_h_k(
    const float* __restrict__ x, const float* __restrict__ W1,
    const float* __restrict__ asf, const float* __restrict__ adf,
    __half* __restrict__ hb, float* __restrict__ es, float* __restrict__ ed) {
  int t = threadIdx.x, w = t >> 6;
  float wc[7];
#pragma unroll
  for (int k = 0; k < 7; ++k) wc[k] = W1[k * HC + t];
  float av = asf[t], dv = adf[t];
  for (int i = blockIdx.x; i < NN; i += gridDim.x) {
    float acc = 0.f;
#pragma unroll
    for (int k = 0; k < 7; ++k) acc = fmaf(x[i * 7 + k], wc[k], acc);
    hb[(size_t)i * HC + t] = __float2half(acc);
    float a = wred_sum(acc * av);
    float d = wred_sum(acc * dv);
    if ((t & 63) == 0) { es[i * HEADS + w] = a; ed[i * HEADS + w] = d; }
  }
}

// ------- GAT aggregate v4: wave-per-node, 4-edge batches (int4 broadcast) -------
__global__ __launch_bounds__(256) void gat_agg256(
    const __half* __restrict__ hb, const float* __restrict__ es,
    const float* __restrict__ ed, const int* __restrict__ offs,
    const int* __restrict__ elist, const float* __restrict__ bias,
    float* __restrict__ out) {
  int t = threadIdx.x, wv = t >> 6, lane = t & 63;
  int hd = lane >> 4;
  float4 bv = ((const float4*)bias)[lane];
  const float2* hb4 = (const float2*)hb;
  int i = blockIdx.x * 4 + wv;
  if (i >= NN) return;
  int base = offs[i], end = offs[i + 1];
  float edv = ed[i * HEADS + hd];
  float denom = 0.f;
  float4 acc = make_float4(0.f, 0.f, 0.f, 0.f);

#define EDGE1(SRC)                                         \
  {                                                        \
    int src_ = (SRC);                                      \
    float ex_ = __expf(lrelu(es[src_ * HEADS + hd] + edv));\
    denom += ex_;                                          \
    float2 raw_ = hb4[(size_t)src_ * 64 + lane];           \
    float2 h01_ = __half22float2(*(__half2*)&raw_.x);      \
    float2 h23_ = __half22float2(*(__half2*)&raw_.y);      \
    acc.x = fmaf(ex_, h01_.x, acc.x);                      \
    acc.y = fmaf(ex_, h01_.y, acc.y);                      \
    acc.z = fmaf(ex_, h23_.x, acc.z);                      \
    acc.w = fmaf(ex_, h23_.y, acc.w);                      \
  }

  int e = base;
  int alim = (base + 3) & ~3;
  for (; e < end && e < alim; ++e) EDGE1(elist[e]);
  for (; e + 4 <= end; e += 4) {
    int4 idx = *(const int4*)&elist[e];  // 16B-aligned broadcast load
    float e0 = es[idx.x * HEADS + hd], e1 = es[idx.y * HEADS + hd];
    float e2 = es[idx.z * HEADS + hd], e3 = es[idx.w * HEADS + hd];
    float2 r0 = hb4[(size_t)idx.x * 64 + lane];
    float2 r1 = hb4[(size_t)idx.y * 64 + lane];
    float2 r2 = hb4[(size_t)idx.z * 64 + lane];
    float2 r3 = hb4[(size_t)idx.w * 64 + lane];
    float x0 = __expf(lrelu(e0 + edv)), x1 = __expf(lrelu(e1 + edv));
    float x2 = __expf(lrelu(e2 + edv)), x3 = __expf(lrelu(e3 + edv));
    denom += (x0 + x1) + (x2 + x3);
    float2 a0 = __half22float2(*(__half2*)&r0.x), b0 = __half22float2(*(__half2*)&r0.y);
    float2 a1 = __half22float2(*(__half2*)&r1.x), b1 = __half22float2(*(__half2*)&r1.y);
    float2 a2 = __half22float2(*(__half2*)&r2.x), b2 = __half22float2(*(__half2*)&r2.y);
    float2 a3 = __half22float2(*(__half2*)&r3.x), b3 = __half22float2(*(__half2*)&r3.y);
    acc.x = fmaf(x0, a0.x, fmaf(x1, a1.x, fmaf(x2, a2.x, fmaf(x3, a3.x, acc.x))));
    acc.y = fmaf(x0, a0.y, fmaf(x1, a1.y, fmaf(x2, a2.y, fmaf(x3, a3.y, acc.y))));
    acc.z = fmaf(x0, b0.x, fmaf(x1, b1.x, fmaf(x2, b2.x, fmaf(x3, b3.x, acc.z))));
    acc.w = fmaf(x0, b0.y, fmaf(x1, b1.y, fmaf(x2, b2.y, fmaf(x3, b3.y, acc.w))));
  }
  for (; e < end; ++e) EDGE1(elist[e]);
#undef EDGE1

  float inv = 1.f / (denom + 1e-16f);
  float4 r;
  r.x = fmaf(acc.x, inv, bv.x);
  r.y = fmaf(acc.y, inv, bv.y);
  r.z = fmaf(acc.z, inv, bv.z);
  r.w = fmaf(acc.w, inv, bv.w);
  ((float4*)(out + (size_t)i * HC))[lane] = r;
}

// ---------------- BatchNorm stats ----------------
__global__ __launch_bounds__(256) void bn_stats_k(const float* __restrict__ X,
                                                  float* __restrict__ sums) {
  int t = threadIdx.x;
  int r0 = blockIdx.x * 64;
  int rend = min(r0 + 64, NN);
  float s = 0.f, q = 0.f;
  for (int r = r0; r < rend; ++r) {
    float v = X[(size_t)r * HC + t];
    s += v;
    q = fmaf(v, v, q);
  }
  atomicAdd(&sums[t], s);
  atomicAdd(&sums[HC + t], q);
}

__global__ void bn_final_k(const float* __restrict__ sums, const float* __restrict__ g,
                           const float* __restrict__ be, float* __restrict__ ab) {
  int t = threadIdx.x;
  float mu = sums[t] * (1.f / NN);
  float var = sums[HC + t] * (1.f / NN) - mu * mu;
  float a = g[t] * rsqrtf(var + 1e-5f);
  ab[t] = a;
  ab[HC + t] = fmaf(-mu, a, be[t]);
}

// ------- MFMA fp16 GEMM: hbuf = relu(affine(A)) @ W2, 128x128 tile -------
// A fp32 [NN][256]; Bh fragment-ordered fp16; out fp16 [NN][256]
__global__ __launch_bounds__(256) void gemm_mfma_k(const float* __restrict__ A,
                                                   const __half* __restrict__ Bh,
                                                   const float* __restrict__ ab,
                                                   __half* __restrict__ Ch) {
  __shared__ __align__(16) __half As[128 * 40];  // 128 rows, stride 40 (pad 8)
  __shared__ float abL[512];
  int t = threadIdx.x;
  abL[t] = ab[t];
  abL[256 + t] = ab[256 + t];
  int wv = t >> 6, lane = t & 63;
  int wm = wv >> 1, wn = wv & 1;
  int m0 = blockIdx.x * 128;
  int ntb = blockIdx.y * 8 + wn * 4;  // n_tile base for this wave
  int srow = t >> 1;                  // staging row 0..127
  int skq = (t & 1) * 16;             // staging k offset 0/16
  int grow = m0 + srow;
  const f16x8* Bf = (const f16x8*)Bh;

  f32x4 acc[4][4];
  f32x4 zf = {0.f, 0.f, 0.f, 0.f};
#pragma unroll
  for (int mt = 0; mt < 4; ++mt)
#pragma unroll
    for (int nt = 0; nt < 4; ++nt) acc[mt][nt] = zf;

  for (int ks = 0; ks < 8; ++ks) {
    int k0 = ks * 32;
    __syncthreads();
    {
      float xv[16];
      if (grow < NN) {
        const float* ap = A + (size_t)grow * HC + k0 + skq;
#pragma unroll
        for (int q = 0; q < 4; ++q) *(float4*)&xv[q * 4] = *(const float4*)(ap + q * 4);
      } else {
#pragma unroll
        for (int j = 0; j < 16; ++j) xv[j] = 0.f;
      }
      f16x8 v0, v1;
#pragma unroll
      for (int j = 0; j < 8; ++j) {
        float a_ = abL[k0 + skq + j], b_ = abL[256 + k0 + skq + j];
        v0[j] = (_Float16)fmaxf(fmaf(xv[j], a_, b_), 0.f);
      }
#pragma unroll
      for (int j = 0; j < 8; ++j) {
        float a_ = abL[k0 + skq + 8 + j], b_ = abL[256 + k0 + skq + 8 + j];
        v1[j] = (_Float16)fmaxf(fmaf(xv[8 + j], a_, b_), 0.f);
      }
      *(f16x8*)&As[srow * 40 + skq] = v0;
      *(f16x8*)&As[srow * 40 + skq + 8] = v1;
    }
    __syncthreads();
    f16x8 af[4], bf[4];
    int lr = wm * 64 + (lane & 15);
    int kk = (lane >> 4) * 8;
#pragma unroll
    for (int mt = 0; mt < 4; ++mt)
      af[mt] = *(const f16x8*)&As[(lr + mt * 16) * 40 + kk];
#pragma unroll
    for (int nt = 0; nt < 4; ++nt)
      bf[nt] = Bf[(size_t)((ntb + nt) * 8 + ks) * 64 + lane];
#pragma unroll
    for (int mt = 0; mt < 4; ++mt)
#pragma unroll
      for (int nt = 0; nt < 4; ++nt)
        acc[mt][nt] = __builtin_amdgcn_mfma_f32_16x16x32_f16(af[mt], bf[nt], acc[mt][nt], 0, 0, 0);
  }

  // epilogue: C[row][col], row=(lane>>4)*4+r within frag, col=lane&15
  int colb = blockIdx.y * 128 + wn * 64 + (lane & 15);
#pragma unroll
  for (int mt = 0; mt < 4; ++mt) {
    int rowb = m0 + wm * 64 + mt * 16 + (lane >> 4) * 4;
#pragma unroll
    for (int nt = 0; nt < 4; ++nt) {
      int col = colb + nt * 16;
#pragma unroll
      for (int r = 0; r < 4; ++r) {
        int row = rowb + r;
        if (row < NN) Ch[(size_t)row * HC + col] = __float2half(acc[mt][nt][r]);
      }
    }
  }
}

// ---------------- e_src/e_dst for layer 2 (fp16 h) ----------------
__global__ __launch_bounds__(256) void esed_k(const __half* __restrict__ hb,
                                              const float* __restrict__ asf,
                                              const float* __restrict__ adf,
                                              float* __restrict__ es,
                                              float* __restrict__ ed) {
  int t = threadIdx.x, w = t >> 6;
  float av = asf[t], dv = adf[t];
  for (int i = blockIdx.x; i < NN; i += gridDim.x) {
    float v = __half2float(hb[(size_t)i * HC + t]);
    float a = wred_sum(v * av);
    float d = wred_sum(v * dv);
    if ((t & 63) == 0) { es[i * HEADS + w] = a; ed[i * HEADS + w] = d; }
  }
}

// ---------------- layer 3: h3 = relu(affine(X)) @ W3, fused e ----------------
__global__ __launch_bounds__(256) void l3_h_k(
    const float* __restrict__ X, const float* __restrict__ ab,
    const float* __restrict__ W3, const float* __restrict__ asf,
    const float* __restrict__ adf, float* __restrict__ h3,
    float* __restrict__ es3, float* __restrict__ ed3) {
  __shared__ float abL[512];
  int t = threadIdx.x;
  abL[t] = ab[t];
  abL[256 + t] = ab[256 + t];
  __syncthreads();
  int g = t >> 5, c = t & 31;
  float av = asf[c], dv = adf[c];
  for (int ib = blockIdx.x; ib * 8 < NN; ib += gridDim.x) {
    int node = ib * 8 + g;
    if (node >= NN) continue;
    float acc = 0.f;
    const float4* xr = (const float4*)(X + (size_t)node * HC);
#pragma unroll 4
    for (int k4 = 0; k4 < 64; ++k4) {
      float4 xv = xr[k4];
      int kb = k4 * 4;
      float x0 = fmaxf(fmaf(xv.x, abL[kb + 0], abL[256 + kb + 0]), 0.f);
      float x1 = fmaxf(fmaf(xv.y, abL[kb + 1], abL[256 + kb + 1]), 0.f);
      float x2 = fmaxf(fmaf(xv.z, abL[kb + 2], abL[256 + kb + 2]), 0.f);
      float x3 = fmaxf(fmaf(xv.w, abL[kb + 3], abL[256 + kb + 3]), 0.f);
      acc = fmaf(x0, W3[(kb + 0) * OUTD + c], acc);
      acc = fmaf(x1, W3[(kb + 1) * OUTD + c], acc);
      acc = fmaf(x2, W3[(kb + 2) * OUTD + c], acc);
      acc = fmaf(x3, W3[(kb + 3) * OUTD + c], acc);
    }
    h3[(size_t)node * OUTD + c] = acc;
    float a = acc * av, d = acc * dv;
#pragma unroll
    for (int off = 16; off; off >>= 1) {
      a += __shfl_xor(a, off);
      d += __shfl_xor(d, off);
    }
    if (c == 0) { es3[node] = a; ed3[node] = d; }
  }
}

// ------- GAT aggregate, heads=1, ch=32: wave-per-node, 2 edges/iter -------
__global__ __launch_bounds__(256) void gat_agg32(
    const float* __restrict__ h3, const float* __restrict__ es3,
    const float* __restrict__ ed3, const int* __restrict__ offs,
    const int* __restrict__ elist, const float* __restrict__ b3,
    float* __restrict__ emb) {
  int t = threadIdx.x, wv = t >> 6, lane = t & 63;
  int eo = lane >> 5, c = lane & 31;
  float bv = b3[c];
  int i = blockIdx.x * 4 + wv;
  if (i >= NN) return;
  int base = offs[i], end = offs[i + 1];
  float edv = ed3[i];
  float denom = 0.f, acc = 0.f;
#pragma unroll 2
  for (int e = base + eo; e < end; e += 2) {
    int src = elist[e];
    float ex = __expf(lrelu(es3[src] + edv));
    denom += ex;
    acc = fmaf(ex, h3[(size_t)src * OUTD + c], acc);
  }
  denom += __shfl_xor(denom, 32);
  acc += __shfl_xor(acc, 32);
  if (eo == 0) emb[(size_t)i * OUTD + c] = acc / (denom + 1e-16f) + bv;
}

// ---------------- MLP head ----------------
__global__ void c1_k(const float* __restrict__ emb, const int* __restrict__ srcn,
                     const float* __restrict__ Wm1, const float* __restrict__ bm1,
                     float* __restrict__ c1) {
  int l = threadIdx.x;  // 64 threads
  int sn = srcn[0];
  float a = bm1[l];
  for (int k = 0; k < 32; ++k) a = fmaf(emb[(size_t)sn * OUTD + k], Wm1[k * 64 + l], a);
  c1[l] = a;
}

__global__ __launch_bounds__(256) void mlp_k(
    const float* __restrict__ emb, const float* __restrict__ c1,
    const float* __restrict__ Wm1, const float* __restrict__ Wm2,
    const float* __restrict__ bm2, const float* __restrict__ Wm3,
    const float* __restrict__ bm3, float* __restrict__ outp) {
  __shared__ float WL1s[32][64];
  __shared__ float WL2s[64][32];
  __shared__ float W3s[32];
  __shared__ float c1s[64];
  int t = threadIdx.x;
  for (int q = t; q < 2048; q += 256) WL1s[q >> 6][q & 63] = Wm1[(32 + (q >> 6)) * 64 + (q & 63)];
  for (int q = t; q < 2048; q += 256) WL2s[q >> 5][q & 31] = Wm2[q];
  if (t < 32) W3s[t] = Wm3[t];
  if (t < 64) c1s[t] = c1[t];
  __syncthreads();
  int wv = t >> 6, lane = t & 63;
  int p = lane >> 5, c = lane & 31;
  float bm2v = bm2[c];
  float bm3v = bm3[0];
  for (int node = blockIdx.x * 4 + wv; node < NN; node += gridDim.x * 4) {
    float zv = (lane < 32) ? emb[(size_t)node * OUTD + lane] : 0.f;
    float a1 = c1s[lane];
#pragma unroll
    for (int k = 0; k < 32; ++k) a1 = fmaf(__shfl(zv, k), WL1s[k][lane], a1);
    float u1 = fmaxf(a1, 0.f);
    float a2 = 0.f;
#pragma unroll
    for (int j = 0; j < 32; ++j) a2 = fmaf(__shfl(u1, p * 32 + j), WL2s[p * 32 + j][c], a2);
    a2 += __shfl_xor(a2, 32);
    float v = 0.f;
    if (lane < 32) {
      float u2 = fmaxf(a2 + bm2v, 0.f);
      v = u2 * W3s[c];
    }
    v = wred_sum(v);
    if (lane == 0) outp[node] = 1.f / (1.f + __expf(-(v + bm3v)));
  }
}

// ---------------- host launcher ----------------
extern "C" void kernel_launch(void* const* d_in, const int* in_sizes, int n_in,
                              void* d_out, int out_size, void* d_ws, size_t ws_size,
                              hipStream_t stream) {
  const float* x   = (const float*)d_in[0];
  const int* eidx  = (const int*)d_in[1];
  const int* srcn  = (const int*)d_in[2];
  const float* W1  = (const float*)d_in[3];
  const float* as1 = (const float*)d_in[4];
  const float* ad1 = (const float*)d_in[5];
  const float* b1  = (const float*)d_in[6];
  const float* g1  = (const float*)d_in[7];
  const float* be1 = (const float*)d_in[8];
  const float* W2  = (const float*)d_in[9];
  const float* as2 = (const float*)d_in[10];
  const float* ad2 = (const float*)d_in[11];
  const float* b2  = (const float*)d_in[12];
  const float* g2  = (const float*)d_in[13];
  const float* be2 = (const float*)d_in[14];
  const float* W3  = (const float*)d_in[15];
  const float* as3 = (const float*)d_in[16];
  const float* ad3 = (const float*)d_in[17];
  const float* b3  = (const float*)d_in[18];
  const float* Wm1 = (const float*)d_in[19];
  const float* bm1 = (const float*)d_in[20];
  const float* Wm2 = (const float*)d_in[21];
  const float* bm2 = (const float*)d_in[22];
  const float* Wm3 = (const float*)d_in[23];
  const float* bm3 = (const float*)d_in[24];
  float* outp = (float*)d_out;

  // workspace carve (float counts multiples of 4 -> 16B alignment preserved)
  float* fw = (float*)d_ws;
  float* bufB   = fw;  fw += (size_t)NN * HC;              // fp32 agg output
  __half* hbuf  = (__half*)fw; fw += (size_t)NN * HC / 2;  // fp16 h
  float* h3     = fw;  fw += (size_t)NN * OUTD;
  float* emb    = fw;  fw += (size_t)NN * OUTD;
  float* es     = fw;  fw += (size_t)NN * HEADS;
  float* ed     = fw;  fw += (size_t)NN * HEADS;
  float* es3    = fw;  fw += NN;
  float* ed3    = fw;  fw += NN;
  float* bnsums = fw;  fw += 2 * HC;
  float* bnab   = fw;  fw += 2 * HC;
  float* c1     = fw;  fw += 64;
  __half* Bh    = (__half*)fw; fw += (size_t)HC * HC / 2;  // swizzled W2 fp16
  int* iw = (int*)fw;
  int* offs   = iw;  iw += NN + 4;   // padded so elist stays 16B-aligned
  int* cursor = iw;  iw += NN;
  int* elist  = iw;  iw += ETOT;
  int* part   = iw;  iw += NN;
  int* bsum   = iw;  iw += 256;
  int* bscan  = iw;  iw += 256;

  const int TB = 256;
  const int gE = (ETOT + TB - 1) / TB;
  const int gN4 = (NN + 3) / 4;

  // ---- CSR build ----
  zero_i32<<<(NN + TB - 1) / TB, TB, 0, stream>>>(cursor, NN);
  hist_k<<<gE, TB, 0, stream>>>(eidx, cursor);
  scan1_k<<<NB1, TB, 0, stream>>>(cursor, part, bsum);
  scan2_k<<<1, TB, 0, stream>>>(bsum, bscan);
  scan3_k<<<NB1, TB, 0, stream>>>(part, bscan, offs, cursor);
  scatter_k<<<gE, TB, 0, stream>>>(eidx, cursor, elist);
  w2_swz_k<<<HC * HC / TB, TB, 0, stream>>>(W2, Bh);

  // ---- layer 1 ----
  l1_h_k<<<2048, TB, 0, stream>>>(x, W1, as1, ad1, hbuf, es, ed);
  gat_agg256<<<gN4, TB, 0, stream>>>(hbuf, es, ed, offs, elist, b1, bufB);
  zero_i32<<<2, TB, 0, stream>>>((int*)bnsums, 2 * HC);
  bn_stats_k<<<(NN + 63) / 64, TB, 0, stream>>>(bufB, bnsums);
  bn_final_k<<<1, TB, 0, stream>>>(bnsums, g1, be1, bnab);

  // ---- layer 2: MFMA GEMM (BN1 affine+relu fused into A staging) ----
  gemm_mfma_k<<<dim3((NN + 127) / 128, HC / 128), TB, 0, stream>>>(bufB, Bh, bnab, hbuf);
  esed_k<<<2048, TB, 0, stream>>>(hbuf, as2, ad2, es, ed);
  gat_agg256<<<gN4, TB, 0, stream>>>(hbuf, es, ed, offs, elist, b2, bufB);
  zero_i32<<<2, TB, 0, stream>>>((int*)bnsums, 2 * HC);
  bn_stats_k<<<(NN + 63) / 64, TB, 0, stream>>>(bufB, bnsums);
  bn_final_k<<<1, TB, 0, stream>>>(bnsums, g2, be2, bnab);

  // ---- layer 3 (BN2 affine+relu fused into l3 X-load) ----
  l3_h_k<<<(NN + 7) / 8, TB, 0, stream>>>(bufB, bnab, W3, as3, ad3, h3, es3, ed3);
  gat_agg32<<<gN4, TB, 0, stream>>>(h3, es3, ed3, offs, elist, b3, emb);

  // ---- MLP head ----
  c1_k<<<1, 64, 0, stream>>>(emb, srcn, Wm1, bm1, c1);
  mlp_k<<<512, TB, 0, stream>>>(emb, c1, Wm1, Wm2, bm2, Wm3, bm3, outp);
}

// Round 5
// 514.031 us; speedup vs baseline: 1.8756x; 1.1471x over previous
//
#include <hip/hip_runtime.h>
#include <hip/hip_fp16.h>
#include <math.h>

#define NN 50000
#define EE 800000
#define ETOT (EE + NN)
#define HC 256
#define HEADS 4
#define OUTD 32
#define NB1 196   // ceil(NN/256)

typedef _Float16 f16x8 __attribute__((ext_vector_type(8)));
typedef float f32x4 __attribute__((ext_vector_type(4)));

// ---------------- utility ----------------
__device__ __forceinline__ float wred_sum(float v) {
#pragma unroll
  for (int off = 32; off; off >>= 1) v += __shfl_xor(v, off);
  return v;
}
__device__ __forceinline__ float lrelu(float x) { return x >= 0.f ? x : 0.2f * x; }

__global__ void zero_i32(int* __restrict__ p, int n) {
  int i = blockIdx.x * blockDim.x + threadIdx.x;
  if (i < n) p[i] = 0;
}

// ---------------- CSR build ----------------
__global__ void hist_k(const int* __restrict__ ei, int* __restrict__ cnt) {
  int e = blockIdx.x * blockDim.x + threadIdx.x;
  if (e >= ETOT) return;
  int d = (e < EE) ? ei[EE + e] : (e - EE);
  atomicAdd(&cnt[d], 1);
}

__global__ void scan1_k(const int* __restrict__ cnt, int* __restrict__ part,
                        int* __restrict__ bsum) {
  __shared__ int s[256];
  int t = threadIdx.x, i = blockIdx.x * 256 + t;
  int v = (i < NN) ? cnt[i] : 0;
  s[t] = v;
  __syncthreads();
#pragma unroll
  for (int off = 1; off < 256; off <<= 1) {
    int u = (t >= off) ? s[t - off] : 0;
    __syncthreads();
    s[t] += u;
    __syncthreads();
  }
  if (i < NN) part[i] = s[t] - v;
  if (t == 255) bsum[blockIdx.x] = s[255];
}

__global__ void scan2_k(const int* __restrict__ bsum, int* __restrict__ bscan) {
  __shared__ int s[256];
  int t = threadIdx.x;
  int v = (t < NB1) ? bsum[t] : 0;
  s[t] = v;
  __syncthreads();
#pragma unroll
  for (int off = 1; off < 256; off <<= 1) {
    int u = (t >= off) ? s[t - off] : 0;
    __syncthreads();
    s[t] += u;
    __syncthreads();
  }
  if (t < NB1) bscan[t] = s[t] - v;
}

__global__ void scan3_k(const int* __restrict__ part, const int* __restrict__ bscan,
                        int* __restrict__ offs, int* __restrict__ cursor) {
  int i = blockIdx.x * 256 + threadIdx.x;
  if (i < NN) {
    int v = part[i] + bscan[blockIdx.x];
    offs[i] = v;
    cursor[i] = v;
  }
  if (i == 0) offs[NN] = ETOT;
}

__global__ void scatter_k(const int* __restrict__ ei, int* __restrict__ cursor,
                          int* __restrict__ elist) {
  int e = blockIdx.x * blockDim.x + threadIdx.x;
  if (e >= ETOT) return;
  int s, d;
  if (e < EE) { s = ei[e]; d = ei[EE + e]; } else { s = d = e - EE; }
  int pos = atomicAdd(&cursor[d], 1);
  elist[pos] = s;
}

// ------- W -> fp16, fragment-ordered for 16x16x32 MFMA B (generic N cols) -------
// Bh index: frag=(n>>4)*8+(k>>5); lane=(n&15)+16*((k>>3)&3); elem=k&7
template <int NCOL>
__global__ __launch_bounds__(256) void wswz_k(const float* __restrict__ W,
                                              __half* __restrict__ Bh) {
  int idx = blockIdx.x * 256 + threadIdx.x;
  if (idx >= HC * NCOL) return;
  int k = idx / NCOL, n = idx % NCOL;
  int frag = (n >> 4) * 8 + (k >> 5);
  int lane = (n & 15) + (((k >> 3) & 3) << 4);
  int elem = k & 7;
  Bh[(frag * 64 + lane) * 8 + elem] = __float2half(W[idx]);
}

// ---------------- layer 1: h = x @ W1 (fp16 out), fused e_src/e_dst ----------------
__global__ __launch_bounds__(256) void l1_h_k(
    const float* __restrict__ x, const float* __restrict__ W1,
    const float* __restrict__ asf, const float* __restrict__ adf,
    __half* __restrict__ hb, float* __restrict__ es, float* __restrict__ ed) {
  int t = threadIdx.x, w = t >> 6;
  float wc[7];
#pragma unroll
  for (int k = 0; k < 7; ++k) wc[k] = W1[k * HC + t];
  float av = asf[t], dv = adf[t];
  for (int i = blockIdx.x; i < NN; i += gridDim.x) {
    float acc = 0.f;
#pragma unroll
    for (int k = 0; k < 7; ++k) acc = fmaf(x[i * 7 + k], wc[k], acc);
    hb[(size_t)i * HC + t] = __float2half(acc);
    float a = wred_sum(acc * av);
    float d = wred_sum(acc * dv);
    if ((t & 63) == 0) { es[i * HEADS + w] = a; ed[i * HEADS + w] = d; }
  }
}

// ------- GAT aggregate v4: wave-per-node, 4-edge batches (int4 broadcast) -------
__global__ __launch_bounds__(256) void gat_agg256(
    const __half* __restrict__ hb, const float* __restrict__ es,
    const float* __restrict__ ed, const int* __restrict__ offs,
    const int* __restrict__ elist, const float* __restrict__ bias,
    float* __restrict__ out) {
  int t = threadIdx.x, wv = t >> 6, lane = t & 63;
  int hd = lane >> 4;
  float4 bv = ((const float4*)bias)[lane];
  const float2* hb4 = (const float2*)hb;
  int i = blockIdx.x * 4 + wv;
  if (i >= NN) return;
  int base = offs[i], end = offs[i + 1];
  float edv = ed[i * HEADS + hd];
  float denom = 0.f;
  float4 acc = make_float4(0.f, 0.f, 0.f, 0.f);

#define EDGE1(SRC)                                         \
  {                                                        \
    int src_ = (SRC);                                      \
    float ex_ = __expf(lrelu(es[src_ * HEADS + hd] + edv));\
    denom += ex_;                                          \
    float2 raw_ = hb4[(size_t)src_ * 64 + lane];           \
    float2 h01_ = __half22float2(*(__half2*)&raw_.x);      \
    float2 h23_ = __half22float2(*(__half2*)&raw_.y);      \
    acc.x = fmaf(ex_, h01_.x, acc.x);                      \
    acc.y = fmaf(ex_, h01_.y, acc.y);                      \
    acc.z = fmaf(ex_, h23_.x, acc.z);                      \
    acc.w = fmaf(ex_, h23_.y, acc.w);                      \
  }

  int e = base;
  int alim = (base + 3) & ~3;
  for (; e < end && e < alim; ++e) EDGE1(elist[e]);
  for (; e + 4 <= end; e += 4) {
    int4 idx = *(const int4*)&elist[e];  // 16B-aligned broadcast load
    float e0 = es[idx.x * HEADS + hd], e1 = es[idx.y * HEADS + hd];
    float e2 = es[idx.z * HEADS + hd], e3 = es[idx.w * HEADS + hd];
    float2 r0 = hb4[(size_t)idx.x * 64 + lane];
    float2 r1 = hb4[(size_t)idx.y * 64 + lane];
    float2 r2 = hb4[(size_t)idx.z * 64 + lane];
    float2 r3 = hb4[(size_t)idx.w * 64 + lane];
    float x0 = __expf(lrelu(e0 + edv)), x1 = __expf(lrelu(e1 + edv));
    float x2 = __expf(lrelu(e2 + edv)), x3 = __expf(lrelu(e3 + edv));
    denom += (x0 + x1) + (x2 + x3);
    float2 a0 = __half22float2(*(__half2*)&r0.x), b0 = __half22float2(*(__half2*)&r0.y);
    float2 a1 = __half22float2(*(__half2*)&r1.x), b1 = __half22float2(*(__half2*)&r1.y);
    float2 a2 = __half22float2(*(__half2*)&r2.x), b2 = __half22float2(*(__half2*)&r2.y);
    float2 a3 = __half22float2(*(__half2*)&r3.x), b3 = __half22float2(*(__half2*)&r3.y);
    acc.x = fmaf(x0, a0.x, fmaf(x1, a1.x, fmaf(x2, a2.x, fmaf(x3, a3.x, acc.x))));
    acc.y = fmaf(x0, a0.y, fmaf(x1, a1.y, fmaf(x2, a2.y, fmaf(x3, a3.y, acc.y))));
    acc.z = fmaf(x0, b0.x, fmaf(x1, b1.x, fmaf(x2, b2.x, fmaf(x3, b3.x, acc.z))));
    acc.w = fmaf(x0, b0.y, fmaf(x1, b1.y, fmaf(x2, b2.y, fmaf(x3, b3.y, acc.w))));
  }
  for (; e < end; ++e) EDGE1(elist[e]);
#undef EDGE1

  float inv = 1.f / (denom + 1e-16f);
  float4 r;
  r.x = fmaf(acc.x, inv, bv.x);
  r.y = fmaf(acc.y, inv, bv.y);
  r.z = fmaf(acc.z, inv, bv.z);
  r.w = fmaf(acc.w, inv, bv.w);
  ((float4*)(out + (size_t)i * HC))[lane] = r;
}

// ---------------- BatchNorm stats ----------------
__global__ __launch_bounds__(256) void bn_stats_k(const float* __restrict__ X,
                                                  float* __restrict__ sums) {
  int t = threadIdx.x;
  int r0 = blockIdx.x * 64;
  int rend = min(r0 + 64, NN);
  float s = 0.f, q = 0.f;
  for (int r = r0; r < rend; ++r) {
    float v = X[(size_t)r * HC + t];
    s += v;
    q = fmaf(v, v, q);
  }
  atomicAdd(&sums[t], s);
  atomicAdd(&sums[HC + t], q);
}

__global__ void bn_final_k(const float* __restrict__ sums, const float* __restrict__ g,
                           const float* __restrict__ be, float* __restrict__ ab) {
  int t = threadIdx.x;
  float mu = sums[t] * (1.f / NN);
  float var = sums[HC + t] * (1.f / NN) - mu * mu;
  float a = g[t] * rsqrtf(var + 1e-5f);
  ab[t] = a;
  ab[HC + t] = fmaf(-mu, a, be[t]);
}

// ------- MFMA fp16 GEMM: hbuf = relu(affine(A)) @ W2, 128x128 tile -------
__global__ __launch_bounds__(256) void gemm_mfma_k(const float* __restrict__ A,
                                                   const __half* __restrict__ Bh,
                                                   const float* __restrict__ ab,
                                                   __half* __restrict__ Ch) {
  __shared__ __align__(16) __half As[128 * 40];  // 128 rows, stride 40 (pad 8)
  __shared__ float abL[512];
  int t = threadIdx.x;
  abL[t] = ab[t];
  abL[256 + t] = ab[256 + t];
  int wv = t >> 6, lane = t & 63;
  int wm = wv >> 1, wn = wv & 1;
  int m0 = blockIdx.x * 128;
  int ntb = blockIdx.y * 8 + wn * 4;
  int srow = t >> 1;
  int skq = (t & 1) * 16;
  int grow = m0 + srow;
  const f16x8* Bf = (const f16x8*)Bh;

  f32x4 acc[4][4];
  f32x4 zf = {0.f, 0.f, 0.f, 0.f};
#pragma unroll
  for (int mt = 0; mt < 4; ++mt)
#pragma unroll
    for (int nt = 0; nt < 4; ++nt) acc[mt][nt] = zf;

  for (int ks = 0; ks < 8; ++ks) {
    int k0 = ks * 32;
    __syncthreads();
    {
      float xv[16];
      if (grow < NN) {
        const float* ap = A + (size_t)grow * HC + k0 + skq;
#pragma unroll
        for (int q = 0; q < 4; ++q) *(float4*)&xv[q * 4] = *(const float4*)(ap + q * 4);
      } else {
#pragma unroll
        for (int j = 0; j < 16; ++j) xv[j] = 0.f;
      }
      f16x8 v0, v1;
#pragma unroll
      for (int j = 0; j < 8; ++j) {
        float a_ = abL[k0 + skq + j], b_ = abL[256 + k0 + skq + j];
        v0[j] = (_Float16)fmaxf(fmaf(xv[j], a_, b_), 0.f);
      }
#pragma unroll
      for (int j = 0; j < 8; ++j) {
        float a_ = abL[k0 + skq + 8 + j], b_ = abL[256 + k0 + skq + 8 + j];
        v1[j] = (_Float16)fmaxf(fmaf(xv[8 + j], a_, b_), 0.f);
      }
      *(f16x8*)&As[srow * 40 + skq] = v0;
      *(f16x8*)&As[srow * 40 + skq + 8] = v1;
    }
    __syncthreads();
    f16x8 af[4], bf[4];
    int lr = wm * 64 + (lane & 15);
    int kk = (lane >> 4) * 8;
#pragma unroll
    for (int mt = 0; mt < 4; ++mt)
      af[mt] = *(const f16x8*)&As[(lr + mt * 16) * 40 + kk];
#pragma unroll
    for (int nt = 0; nt < 4; ++nt)
      bf[nt] = Bf[(size_t)((ntb + nt) * 8 + ks) * 64 + lane];
#pragma unroll
    for (int mt = 0; mt < 4; ++mt)
#pragma unroll
      for (int nt = 0; nt < 4; ++nt)
        acc[mt][nt] = __builtin_amdgcn_mfma_f32_16x16x32_f16(af[mt], bf[nt], acc[mt][nt], 0, 0, 0);
  }

  int colb = blockIdx.y * 128 + wn * 64 + (lane & 15);
#pragma unroll
  for (int mt = 0; mt < 4; ++mt) {
    int rowb = m0 + wm * 64 + mt * 16 + (lane >> 4) * 4;
#pragma unroll
    for (int nt = 0; nt < 4; ++nt) {
      int col = colb + nt * 16;
#pragma unroll
      for (int r = 0; r < 4; ++r) {
        int row = rowb + r;
        if (row < NN) Ch[(size_t)row * HC + col] = __float2half(acc[mt][nt][r]);
      }
    }
  }
}

// ------- layer 3 MFMA: h3 = relu(affine(X)) @ W3, 128x32 tile, fp32 out -------
__global__ __launch_bounds__(256) void l3_mfma_k(const float* __restrict__ A,
                                                 const __half* __restrict__ Bh,
                                                 const float* __restrict__ ab,
                                                 float* __restrict__ h3) {
  __shared__ __align__(16) __half As[128 * 40];
  __shared__ float abL[512];
  int t = threadIdx.x;
  abL[t] = ab[t];
  abL[256 + t] = ab[256 + t];
  int wv = t >> 6, lane = t & 63;
  int m0 = blockIdx.x * 128;
  int srow = t >> 1;
  int skq = (t & 1) * 16;
  int grow = m0 + srow;
  const f16x8* Bf = (const f16x8*)Bh;

  f32x4 acc[2][2];
  f32x4 zf = {0.f, 0.f, 0.f, 0.f};
#pragma unroll
  for (int mt = 0; mt < 2; ++mt)
#pragma unroll
    for (int nt = 0; nt < 2; ++nt) acc[mt][nt] = zf;

  for (int ks = 0; ks < 8; ++ks) {
    int k0 = ks * 32;
    __syncthreads();
    {
      float xv[16];
      if (grow < NN) {
        const float* ap = A + (size_t)grow * HC + k0 + skq;
#pragma unroll
        for (int q = 0; q < 4; ++q) *(float4*)&xv[q * 4] = *(const float4*)(ap + q * 4);
      } else {
#pragma unroll
        for (int j = 0; j < 16; ++j) xv[j] = 0.f;
      }
      f16x8 v0, v1;
#pragma unroll
      for (int j = 0; j < 8; ++j) {
        float a_ = abL[k0 + skq + j], b_ = abL[256 + k0 + skq + j];
        v0[j] = (_Float16)fmaxf(fmaf(xv[j], a_, b_), 0.f);
      }
#pragma unroll
      for (int j = 0; j < 8; ++j) {
        float a_ = abL[k0 + skq + 8 + j], b_ = abL[256 + k0 + skq + 8 + j];
        v1[j] = (_Float16)fmaxf(fmaf(xv[8 + j], a_, b_), 0.f);
      }
      *(f16x8*)&As[srow * 40 + skq] = v0;
      *(f16x8*)&As[srow * 40 + skq + 8] = v1;
    }
    __syncthreads();
    f16x8 af[2], bf[2];
    int lr = wv * 32 + (lane & 15);
    int kk = (lane >> 4) * 8;
#pragma unroll
    for (int mt = 0; mt < 2; ++mt)
      af[mt] = *(const f16x8*)&As[(lr + mt * 16) * 40 + kk];
#pragma unroll
    for (int nt = 0; nt < 2; ++nt)
      bf[nt] = Bf[(size_t)(nt * 8 + ks) * 64 + lane];
#pragma unroll
    for (int mt = 0; mt < 2; ++mt)
#pragma unroll
      for (int nt = 0; nt < 2; ++nt)
        acc[mt][nt] = __builtin_amdgcn_mfma_f32_16x16x32_f16(af[mt], bf[nt], acc[mt][nt], 0, 0, 0);
  }

#pragma unroll
  for (int mt = 0; mt < 2; ++mt) {
    int rowb = m0 + wv * 32 + mt * 16 + (lane >> 4) * 4;
#pragma unroll
    for (int nt = 0; nt < 2; ++nt) {
      int col = nt * 16 + (lane & 15);
#pragma unroll
      for (int r = 0; r < 4; ++r) {
        int row = rowb + r;
        if (row < NN) h3[(size_t)row * OUTD + col] = acc[mt][nt][r];
      }
    }
  }
}

// ---------------- es3/ed3 from h3 (32-lane row reduce, 8 nodes/block) ----------------
__global__ __launch_bounds__(256) void esed3_k(const float* __restrict__ h3,
                                               const float* __restrict__ asf,
                                               const float* __restrict__ adf,
                                               float* __restrict__ es3,
                                               float* __restrict__ ed3) {
  int t = threadIdx.x;
  int node = blockIdx.x * 8 + (t >> 5);
  int c = t & 31;
  if (node >= NN) return;
  float v = h3[(size_t)node * OUTD + c];
  float a = v * asf[c], d = v * adf[c];
#pragma unroll
  for (int off = 16; off; off >>= 1) {
    a += __shfl_xor(a, off);
    d += __shfl_xor(d, off);
  }
  if (c == 0) { es3[node] = a; ed3[node] = d; }
}

// ---------------- e_src/e_dst for layer 2 (fp16 h) ----------------
__global__ __launch_bounds__(256) void esed_k(const __half* __restrict__ hb,
                                              const float* __restrict__ asf,
                                              const float* __restrict__ adf,
                                              float* __restrict__ es,
                                              float* __restrict__ ed) {
  int t = threadIdx.x, w = t >> 6;
  float av = asf[t], dv = adf[t];
  for (int i = blockIdx.x; i < NN; i += gridDim.x) {
    float v = __half2float(hb[(size_t)i * HC + t]);
    float a = wred_sum(v * av);
    float d = wred_sum(v * dv);
    if ((t & 63) == 0) { es[i * HEADS + w] = a; ed[i * HEADS + w] = d; }
  }
}

// ------- GAT aggregate, heads=1, ch=32: wave-per-node, 2 edges/iter -------
__global__ __launch_bounds__(256) void gat_agg32(
    const float* __restrict__ h3, const float* __restrict__ es3,
    const float* __restrict__ ed3, const int* __restrict__ offs,
    const int* __restrict__ elist, const float* __restrict__ b3,
    float* __restrict__ emb) {
  int t = threadIdx.x, wv = t >> 6, lane = t & 63;
  int eo = lane >> 5, c = lane & 31;
  float bv = b3[c];
  int i = blockIdx.x * 4 + wv;
  if (i >= NN) return;
  int base = offs[i], end = offs[i + 1];
  float edv = ed3[i];
  float denom = 0.f, acc = 0.f;
#pragma unroll 2
  for (int e = base + eo; e < end; e += 2) {
    int src = elist[e];
    float ex = __expf(lrelu(es3[src] + edv));
    denom += ex;
    acc = fmaf(ex, h3[(size_t)src * OUTD + c], acc);
  }
  denom += __shfl_xor(denom, 32);
  acc += __shfl_xor(acc, 32);
  if (eo == 0) emb[(size_t)i * OUTD + c] = acc / (denom + 1e-16f) + bv;
}

// ---------------- MLP head ----------------
__global__ void c1_k(const float* __restrict__ emb, const int* __restrict__ srcn,
                     const float* __restrict__ Wm1, const float* __restrict__ bm1,
                     float* __restrict__ c1) {
  int l = threadIdx.x;  // 64 threads
  int sn = srcn[0];
  float a = bm1[l];
  for (int k = 0; k < 32; ++k) a = fmaf(emb[(size_t)sn * OUTD + k], Wm1[k * 64 + l], a);
  c1[l] = a;
}

__global__ __launch_bounds__(256) void mlp_k(
    const float* __restrict__ emb, const float* __restrict__ c1,
    const float* __restrict__ Wm1, const float* __restrict__ Wm2,
    const float* __restrict__ bm2, const float* __restrict__ Wm3,
    const float* __restrict__ bm3, float* __restrict__ outp) {
  __shared__ float WL1s[32][64];
  __shared__ float WL2s[64][32];
  __shared__ float W3s[32];
  __shared__ float c1s[64];
  int t = threadIdx.x;
  for (int q = t; q < 2048; q += 256) WL1s[q >> 6][q & 63] = Wm1[(32 + (q >> 6)) * 64 + (q & 63)];
  for (int q = t; q < 2048; q += 256) WL2s[q >> 5][q & 31] = Wm2[q];
  if (t < 32) W3s[t] = Wm3[t];
  if (t < 64) c1s[t] = c1[t];
  __syncthreads();
  int wv = t >> 6, lane = t & 63;
  int p = lane >> 5, c = lane & 31;
  float bm2v = bm2[c];
  float bm3v = bm3[0];
  for (int node = blockIdx.x * 4 + wv; node < NN; node += gridDim.x * 4) {
    float zv = (lane < 32) ? emb[(size_t)node * OUTD + lane] : 0.f;
    float a1 = c1s[lane];
#pragma unroll
    for (int k = 0; k < 32; ++k) a1 = fmaf(__shfl(zv, k), WL1s[k][lane], a1);
    float u1 = fmaxf(a1, 0.f);
    float a2 = 0.f;
#pragma unroll
    for (int j = 0; j < 32; ++j) a2 = fmaf(__shfl(u1, p * 32 + j), WL2s[p * 32 + j][c], a2);
    a2 += __shfl_xor(a2, 32);
    float v = 0.f;
    if (lane < 32) {
      float u2 = fmaxf(a2 + bm2v, 0.f);
      v = u2 * W3s[c];
    }
    v = wred_sum(v);
    if (lane == 0) outp[node] = 1.f / (1.f + __expf(-(v + bm3v)));
  }
}

// ---------------- host launcher ----------------
extern "C" void kernel_launch(void* const* d_in, const int* in_sizes, int n_in,
                              void* d_out, int out_size, void* d_ws, size_t ws_size,
                              hipStream_t stream) {
  const float* x   = (const float*)d_in[0];
  const int* eidx  = (const int*)d_in[1];
  const int* srcn  = (const int*)d_in[2];
  const float* W1  = (const float*)d_in[3];
  const float* as1 = (const float*)d_in[4];
  const float* ad1 = (const float*)d_in[5];
  const float* b1  = (const float*)d_in[6];
  const float* g1  = (const float*)d_in[7];
  const float* be1 = (const float*)d_in[8];
  const float* W2  = (const float*)d_in[9];
  const float* as2 = (const float*)d_in[10];
  const float* ad2 = (const float*)d_in[11];
  const float* b2  = (const float*)d_in[12];
  const float* g2  = (const float*)d_in[13];
  const float* be2 = (const float*)d_in[14];
  const float* W3  = (const float*)d_in[15];
  const float* as3 = (const float*)d_in[16];
  const float* ad3 = (const float*)d_in[17];
  const float* b3  = (const float*)d_in[18];
  const float* Wm1 = (const float*)d_in[19];
  const float* bm1 = (const float*)d_in[20];
  const float* Wm2 = (const float*)d_in[21];
  const float* bm2 = (const float*)d_in[22];
  const float* Wm3 = (const float*)d_in[23];
  const float* bm3 = (const float*)d_in[24];
  float* outp = (float*)d_out;

  // workspace carve (float counts multiples of 4 -> 16B alignment preserved)
  float* fw = (float*)d_ws;
  float* bufB   = fw;  fw += (size_t)NN * HC;              // fp32 agg output
  __half* hbuf  = (__half*)fw; fw += (size_t)NN * HC / 2;  // fp16 h
  float* h3     = fw;  fw += (size_t)NN * OUTD;
  float* emb    = fw;  fw += (size_t)NN * OUTD;
  float* es     = fw;  fw += (size_t)NN * HEADS;
  float* ed     = fw;  fw += (size_t)NN * HEADS;
  float* es3    = fw;  fw += NN;
  float* ed3    = fw;  fw += NN;
  float* bnsums = fw;  fw += 2 * HC;
  float* bnab   = fw;  fw += 2 * HC;
  float* c1     = fw;  fw += 64;
  __half* Bh    = (__half*)fw; fw += (size_t)HC * HC / 2;  // swizzled W2 fp16
  __half* Bh3   = (__half*)fw; fw += (size_t)HC * OUTD / 2; // swizzled W3 fp16
  int* iw = (int*)fw;
  int* offs   = iw;  iw += NN + 4;   // padded so elist stays 16B-aligned
  int* cursor = iw;  iw += NN;
  int* elist  = iw;  iw += ETOT;
  int* part   = iw;  iw += NN;
  int* bsum   = iw;  iw += 256;
  int* bscan  = iw;  iw += 256;

  const int TB = 256;
  const int gE = (ETOT + TB - 1) / TB;
  const int gN4 = (NN + 3) / 4;

  // ---- CSR build ----
  zero_i32<<<(NN + TB - 1) / TB, TB, 0, stream>>>(cursor, NN);
  hist_k<<<gE, TB, 0, stream>>>(eidx, cursor);
  scan1_k<<<NB1, TB, 0, stream>>>(cursor, part, bsum);
  scan2_k<<<1, TB, 0, stream>>>(bsum, bscan);
  scan3_k<<<NB1, TB, 0, stream>>>(part, bscan, offs, cursor);
  scatter_k<<<gE, TB, 0, stream>>>(eidx, cursor, elist);
  wswz_k<HC><<<HC * HC / TB, TB, 0, stream>>>(W2, Bh);
  wswz_k<OUTD><<<HC * OUTD / TB, TB, 0, stream>>>(W3, Bh3);

  // ---- layer 1 ----
  l1_h_k<<<2048, TB, 0, stream>>>(x, W1, as1, ad1, hbuf, es, ed);
  gat_agg256<<<gN4, TB, 0, stream>>>(hbuf, es, ed, offs, elist, b1, bufB);
  zero_i32<<<2, TB, 0, stream>>>((int*)bnsums, 2 * HC);
  bn_stats_k<<<(NN + 63) / 64, TB, 0, stream>>>(bufB, bnsums);
  bn_final_k<<<1, TB, 0, stream>>>(bnsums, g1, be1, bnab);

  // ---- layer 2: MFMA GEMM (BN1 affine+relu fused into A staging) ----
  gemm_mfma_k<<<dim3((NN + 127) / 128, HC / 128), TB, 0, stream>>>(bufB, Bh, bnab, hbuf);
  esed_k<<<2048, TB, 0, stream>>>(hbuf, as2, ad2, es, ed);
  gat_agg256<<<gN4, TB, 0, stream>>>(hbuf, es, ed, offs, elist, b2, bufB);
  zero_i32<<<2, TB, 0, stream>>>((int*)bnsums, 2 * HC);
  bn_stats_k<<<(NN + 63) / 64, TB, 0, stream>>>(bufB, bnsums);
  bn_final_k<<<1, TB, 0, stream>>>(bnsums, g2, be2, bnab);

  // ---- layer 3: MFMA (BN2 affine+relu fused into A staging) ----
  l3_mfma_k<<<(NN + 127) / 128, TB, 0, stream>>>(bufB, Bh3, bnab, h3);
  esed3_k<<<(NN + 7) / 8, TB, 0, stream>>>(h3, as3, ad3, es3, ed3);
  gat_agg32<<<gN4, TB, 0, stream>>>(h3, es3, ed3, offs, elist, b3, emb);

  // ---- MLP head ----
  c1_k<<<1, 64, 0, stream>>>(emb, srcn, Wm1, bm1, c1);
  mlp_k<<<512, TB, 0, stream>>>(emb, c1, Wm1, Wm2, bm2, Wm3, bm3, outp);
}

// Round 6
// 464.047 us; speedup vs baseline: 2.0776x; 1.1077x over previous
//
#include <hip/hip_runtime.h>
#include <hip/hip_fp16.h>
#include <math.h>

#define NN 50000
#define EE 800000
#define ETOT (EE + NN)
#define HC 256
#define HEADS 4
#define OUTD 32
#define NB1 196   // ceil(NN/256)

typedef _Float16 f16x8 __attribute__((ext_vector_type(8)));
typedef float f32x4 __attribute__((ext_vector_type(4)));

// ---------------- utility ----------------
__device__ __forceinline__ float wred_sum(float v) {
#pragma unroll
  for (int off = 32; off; off >>= 1) v += __shfl_xor(v, off);
  return v;
}
__device__ __forceinline__ float qred16(float v) {
#pragma unroll
  for (int off = 1; off < 16; off <<= 1) v += __shfl_xor(v, off);
  return v;
}
__device__ __forceinline__ float lrelu(float x) { return x >= 0.f ? x : 0.2f * x; }

__global__ void zero_i32(int* __restrict__ p, int n) {
  int i = blockIdx.x * blockDim.x + threadIdx.x;
  if (i < n) p[i] = 0;
}

// ---------------- CSR build ----------------
__global__ void hist_k(const int* __restrict__ ei, int* __restrict__ cnt) {
  int e = blockIdx.x * blockDim.x + threadIdx.x;
  if (e >= ETOT) return;
  int d = (e < EE) ? ei[EE + e] : (e - EE);
  atomicAdd(&cnt[d], 1);
}

__global__ void scan1_k(const int* __restrict__ cnt, int* __restrict__ part,
                        int* __restrict__ bsum) {
  __shared__ int s[256];
  int t = threadIdx.x, i = blockIdx.x * 256 + t;
  int v = (i < NN) ? cnt[i] : 0;
  s[t] = v;
  __syncthreads();
#pragma unroll
  for (int off = 1; off < 256; off <<= 1) {
    int u = (t >= off) ? s[t - off] : 0;
    __syncthreads();
    s[t] += u;
    __syncthreads();
  }
  if (i < NN) part[i] = s[t] - v;
  if (t == 255) bsum[blockIdx.x] = s[255];
}

__global__ void scan2_k(const int* __restrict__ bsum, int* __restrict__ bscan) {
  __shared__ int s[256];
  int t = threadIdx.x;
  int v = (t < NB1) ? bsum[t] : 0;
  s[t] = v;
  __syncthreads();
#pragma unroll
  for (int off = 1; off < 256; off <<= 1) {
    int u = (t >= off) ? s[t - off] : 0;
    __syncthreads();
    s[t] += u;
    __syncthreads();
  }
  if (t < NB1) bscan[t] = s[t] - v;
}

__global__ void scan3_k(const int* __restrict__ part, const int* __restrict__ bscan,
                        int* __restrict__ offs, int* __restrict__ cursor) {
  int i = blockIdx.x * 256 + threadIdx.x;
  if (i < NN) {
    int v = part[i] + bscan[blockIdx.x];
    offs[i] = v;
    cursor[i] = v;
  }
  if (i == 0) offs[NN] = ETOT;
}

__global__ void scatter_k(const int* __restrict__ ei, int* __restrict__ cursor,
                          int* __restrict__ elist) {
  int e = blockIdx.x * blockDim.x + threadIdx.x;
  if (e >= ETOT) return;
  int s, d;
  if (e < EE) { s = ei[e]; d = ei[EE + e]; } else { s = d = e - EE; }
  int pos = atomicAdd(&cursor[d], 1);
  elist[pos] = s;
}

// ------- W -> fp16, fragment-ordered for 16x16x32 MFMA B (generic N cols) -------
template <int NCOL>
__global__ __launch_bounds__(256) void wswz_k(const float* __restrict__ W,
                                              __half* __restrict__ Bh) {
  int idx = blockIdx.x * 256 + threadIdx.x;
  if (idx >= HC * NCOL) return;
  int k = idx / NCOL, n = idx % NCOL;
  int frag = (n >> 4) * 8 + (k >> 5);
  int lane = (n & 15) + (((k >> 3) & 3) << 4);
  int elem = k & 7;
  Bh[(frag * 64 + lane) * 8 + elem] = __float2half(W[idx]);
}

// ---------------- layer 1: h = x @ W1 (fp16 out), fused e_src/e_dst ----------------
__global__ __launch_bounds__(256) void l1_h_k(
    const float* __restrict__ x, const float* __restrict__ W1,
    const float* __restrict__ asf, const float* __restrict__ adf,
    __half* __restrict__ hb, float* __restrict__ es, float* __restrict__ ed) {
  int t = threadIdx.x, w = t >> 6;
  float wc[7];
#pragma unroll
  for (int k = 0; k < 7; ++k) wc[k] = W1[k * HC + t];
  float av = asf[t], dv = adf[t];
  for (int i = blockIdx.x; i < NN; i += gridDim.x) {
    float acc = 0.f;
#pragma unroll
    for (int k = 0; k < 7; ++k) acc = fmaf(x[i * 7 + k], wc[k], acc);
    hb[(size_t)i * HC + t] = __float2half(acc);
    float a = wred_sum(acc * av);
    float d = wred_sum(acc * dv);
    if ((t & 63) == 0) { es[i * HEADS + w] = a; ed[i * HEADS + w] = d; }
  }
}

// ------- GAT aggregate v5: wave-per-node, 8-edge batches, fp16 in/out -------
__global__ __launch_bounds__(256) void gat_agg256(
    const __half* __restrict__ hb, const float* __restrict__ es,
    const float* __restrict__ ed, const int* __restrict__ offs,
    const int* __restrict__ elist, const float* __restrict__ bias,
    __half* __restrict__ out) {
  int t = threadIdx.x, wv = t >> 6, lane = t & 63;
  int hd = lane >> 4;
  float4 bv = ((const float4*)bias)[lane];
  const float2* hb4 = (const float2*)hb;
  int i = blockIdx.x * 4 + wv;
  if (i >= NN) return;
  int base = offs[i], end = offs[i + 1];
  float edv = ed[i * HEADS + hd];
  float denom = 0.f;
  float4 acc = make_float4(0.f, 0.f, 0.f, 0.f);

#define ACC1(X_, R_)                                   \
  {                                                    \
    float2 h01_ = __half22float2(*(__half2*)&R_.x);    \
    float2 h23_ = __half22float2(*(__half2*)&R_.y);    \
    acc.x = fmaf(X_, h01_.x, acc.x);                   \
    acc.y = fmaf(X_, h01_.y, acc.y);                   \
    acc.z = fmaf(X_, h23_.x, acc.z);                   \
    acc.w = fmaf(X_, h23_.y, acc.w);                   \
  }
#define EDGE1(SRC)                                          \
  {                                                         \
    int src_ = (SRC);                                       \
    float ex_ = __expf(lrelu(es[src_ * HEADS + hd] + edv)); \
    denom += ex_;                                           \
    float2 raw_ = hb4[(size_t)src_ * 64 + lane];            \
    ACC1(ex_, raw_);                                        \
  }

  int e = base;
  int alim = (base + 3) & ~3;
  for (; e < end && e < alim; ++e) EDGE1(elist[e]);
  for (; e + 8 <= end; e += 8) {
    int4 ia = *(const int4*)&elist[e];
    int4 ib = *(const int4*)&elist[e + 4];
    float f0 = es[ia.x * HEADS + hd], f1 = es[ia.y * HEADS + hd];
    float f2 = es[ia.z * HEADS + hd], f3 = es[ia.w * HEADS + hd];
    float f4 = es[ib.x * HEADS + hd], f5 = es[ib.y * HEADS + hd];
    float f6 = es[ib.z * HEADS + hd], f7 = es[ib.w * HEADS + hd];
    float2 r0 = hb4[(size_t)ia.x * 64 + lane];
    float2 r1 = hb4[(size_t)ia.y * 64 + lane];
    float2 r2 = hb4[(size_t)ia.z * 64 + lane];
    float2 r3 = hb4[(size_t)ia.w * 64 + lane];
    float2 r4 = hb4[(size_t)ib.x * 64 + lane];
    float2 r5 = hb4[(size_t)ib.y * 64 + lane];
    float2 r6 = hb4[(size_t)ib.z * 64 + lane];
    float2 r7 = hb4[(size_t)ib.w * 64 + lane];
    float x0 = __expf(lrelu(f0 + edv)), x1 = __expf(lrelu(f1 + edv));
    float x2 = __expf(lrelu(f2 + edv)), x3 = __expf(lrelu(f3 + edv));
    float x4 = __expf(lrelu(f4 + edv)), x5 = __expf(lrelu(f5 + edv));
    float x6 = __expf(lrelu(f6 + edv)), x7 = __expf(lrelu(f7 + edv));
    denom += ((x0 + x1) + (x2 + x3)) + ((x4 + x5) + (x6 + x7));
    ACC1(x0, r0); ACC1(x1, r1); ACC1(x2, r2); ACC1(x3, r3);
    ACC1(x4, r4); ACC1(x5, r5); ACC1(x6, r6); ACC1(x7, r7);
  }
  for (; e + 4 <= end; e += 4) {
    int4 ia = *(const int4*)&elist[e];
    float f0 = es[ia.x * HEADS + hd], f1 = es[ia.y * HEADS + hd];
    float f2 = es[ia.z * HEADS + hd], f3 = es[ia.w * HEADS + hd];
    float2 r0 = hb4[(size_t)ia.x * 64 + lane];
    float2 r1 = hb4[(size_t)ia.y * 64 + lane];
    float2 r2 = hb4[(size_t)ia.z * 64 + lane];
    float2 r3 = hb4[(size_t)ia.w * 64 + lane];
    float x0 = __expf(lrelu(f0 + edv)), x1 = __expf(lrelu(f1 + edv));
    float x2 = __expf(lrelu(f2 + edv)), x3 = __expf(lrelu(f3 + edv));
    denom += (x0 + x1) + (x2 + x3);
    ACC1(x0, r0); ACC1(x1, r1); ACC1(x2, r2); ACC1(x3, r3);
  }
  for (; e < end; ++e) EDGE1(elist[e]);
#undef EDGE1
#undef ACC1

  float inv = 1.f / (denom + 1e-16f);
  __half2 o01 = __floats2half2_rn(fmaf(acc.x, inv, bv.x), fmaf(acc.y, inv, bv.y));
  __half2 o23 = __floats2half2_rn(fmaf(acc.z, inv, bv.z), fmaf(acc.w, inv, bv.w));
  uint2 pk;
  pk.x = *(unsigned int*)&o01;
  pk.y = *(unsigned int*)&o23;
  ((uint2*)(out + (size_t)i * HC))[lane] = pk;
}

// ---------------- BatchNorm stats (fp16 input) ----------------
__global__ __launch_bounds__(256) void bn_stats_k(const __half* __restrict__ X,
                                                  float* __restrict__ sums) {
  int t = threadIdx.x;
  int r0 = blockIdx.x * 64;
  int rend = min(r0 + 64, NN);
  float s = 0.f, q = 0.f;
  for (int r = r0; r < rend; ++r) {
    float v = __half2float(X[(size_t)r * HC + t]);
    s += v;
    q = fmaf(v, v, q);
  }
  atomicAdd(&sums[t], s);
  atomicAdd(&sums[HC + t], q);
}

__global__ void bn_final_k(const float* __restrict__ sums, const float* __restrict__ g,
                           const float* __restrict__ be, float* __restrict__ ab) {
  int t = threadIdx.x;
  float mu = sums[t] * (1.f / NN);
  float var = sums[HC + t] * (1.f / NN) - mu * mu;
  float a = g[t] * rsqrtf(var + 1e-5f);
  ab[t] = a;
  ab[HC + t] = fmaf(-mu, a, be[t]);
}

// ------- MFMA fp16 GEMM: hbuf = relu(affine(A)) @ W2, 128x128 tile -------
// A fp16 [NN][256]; fused es/ed epilogue (each wave's 64 cols = one head)
__global__ __launch_bounds__(256) void gemm_mfma_k(const __half* __restrict__ A,
                                                   const __half* __restrict__ Bh,
                                                   const float* __restrict__ ab,
                                                   const float* __restrict__ asf,
                                                   const float* __restrict__ adf,
                                                   __half* __restrict__ Ch,
                                                   float* __restrict__ es,
                                                   float* __restrict__ ed) {
  __shared__ __align__(16) __half As[128 * 40];  // 128 rows, stride 40 (pad 8)
  __shared__ float abL[512];
  int t = threadIdx.x;
  abL[t] = ab[t];
  abL[256 + t] = ab[256 + t];
  int wv = t >> 6, lane = t & 63;
  int wm = wv >> 1, wn = wv & 1;
  int m0 = blockIdx.x * 128;
  int ntb = blockIdx.y * 8 + wn * 4;
  int srow = t >> 1;
  int skq = (t & 1) * 16;
  int grow = m0 + srow;
  const f16x8* Bf = (const f16x8*)Bh;

  f32x4 acc[4][4];
  f32x4 zf = {0.f, 0.f, 0.f, 0.f};
#pragma unroll
  for (int mt = 0; mt < 4; ++mt)
#pragma unroll
    for (int nt = 0; nt < 4; ++nt) acc[mt][nt] = zf;

  for (int ks = 0; ks < 8; ++ks) {
    int k0 = ks * 32;
    __syncthreads();
    {
      float xv[16];
      if (grow < NN) {
        const __half* ap = A + (size_t)grow * HC + k0 + skq;
        __half2 hp[8];
        *(uint4*)&hp[0] = *(const uint4*)ap;
        *(uint4*)&hp[4] = *(const uint4*)(ap + 8);
#pragma unroll
        for (int j = 0; j < 8; ++j) {
          float2 f = __half22float2(hp[j]);
          xv[2 * j] = f.x;
          xv[2 * j + 1] = f.y;
        }
      } else {
#pragma unroll
        for (int j = 0; j < 16; ++j) xv[j] = 0.f;
      }
      f16x8 v0, v1;
#pragma unroll
      for (int j = 0; j < 8; ++j) {
        float a_ = abL[k0 + skq + j], b_ = abL[256 + k0 + skq + j];
        v0[j] = (_Float16)fmaxf(fmaf(xv[j], a_, b_), 0.f);
      }
#pragma unroll
      for (int j = 0; j < 8; ++j) {
        float a_ = abL[k0 + skq + 8 + j], b_ = abL[256 + k0 + skq + 8 + j];
        v1[j] = (_Float16)fmaxf(fmaf(xv[8 + j], a_, b_), 0.f);
      }
      *(f16x8*)&As[srow * 40 + skq] = v0;
      *(f16x8*)&As[srow * 40 + skq + 8] = v1;
    }
    __syncthreads();
    f16x8 af[4], bf[4];
    int lr = wm * 64 + (lane & 15);
    int kk = (lane >> 4) * 8;
#pragma unroll
    for (int mt = 0; mt < 4; ++mt)
      af[mt] = *(const f16x8*)&As[(lr + mt * 16) * 40 + kk];
#pragma unroll
    for (int nt = 0; nt < 4; ++nt)
      bf[nt] = Bf[(size_t)((ntb + nt) * 8 + ks) * 64 + lane];
#pragma unroll
    for (int mt = 0; mt < 4; ++mt)
#pragma unroll
      for (int nt = 0; nt < 4; ++nt)
        acc[mt][nt] = __builtin_amdgcn_mfma_f32_16x16x32_f16(af[mt], bf[nt], acc[mt][nt], 0, 0, 0);
  }

  int colb = blockIdx.y * 128 + wn * 64 + (lane & 15);
  // ---- C store (fp16) ----
#pragma unroll
  for (int mt = 0; mt < 4; ++mt) {
    int rowb = m0 + wm * 64 + mt * 16 + (lane >> 4) * 4;
#pragma unroll
    for (int nt = 0; nt < 4; ++nt) {
      int col = colb + nt * 16;
#pragma unroll
      for (int r = 0; r < 4; ++r) {
        int row = rowb + r;
        if (row < NN) Ch[(size_t)row * HC + col] = __float2half(acc[mt][nt][r]);
      }
    }
  }
  // ---- fused es/ed: this wave's 64 cols = head (blockIdx.y*2 + wn) ----
  float asv[4], adv[4];
#pragma unroll
  for (int nt = 0; nt < 4; ++nt) {
    asv[nt] = asf[colb + nt * 16];
    adv[nt] = adf[colb + nt * 16];
  }
  int head = (blockIdx.y << 1) | wn;
#pragma unroll
  for (int mt = 0; mt < 4; ++mt) {
    int rowb = m0 + wm * 64 + mt * 16 + (lane >> 4) * 4;
#pragma unroll
    for (int r = 0; r < 4; ++r) {
      float pe = 0.f, pd = 0.f;
#pragma unroll
      for (int nt = 0; nt < 4; ++nt) {
        pe = fmaf(acc[mt][nt][r], asv[nt], pe);
        pd = fmaf(acc[mt][nt][r], adv[nt], pd);
      }
      pe = qred16(pe);
      pd = qred16(pd);
      int row = rowb + r;
      if ((lane & 15) == 0 && row < NN) {
        es[row * HEADS + head] = pe;
        ed[row * HEADS + head] = pd;
      }
    }
  }
}

// ------- layer 3 MFMA: h3 = relu(affine(X)) @ W3, fp16 out, fused es3/ed3 -------
__global__ __launch_bounds__(256) void l3_mfma_k(const __half* __restrict__ A,
                                                 const __half* __restrict__ Bh,
                                                 const float* __restrict__ ab,
                                                 const float* __restrict__ asf,
                                                 const float* __restrict__ adf,
                                                 __half* __restrict__ h3,
                                                 float* __restrict__ es3,
                                                 float* __restrict__ ed3) {
  __shared__ __align__(16) __half As[128 * 40];
  __shared__ float abL[512];
  int t = threadIdx.x;
  abL[t] = ab[t];
  abL[256 + t] = ab[256 + t];
  int wv = t >> 6, lane = t & 63;
  int m0 = blockIdx.x * 128;
  int srow = t >> 1;
  int skq = (t & 1) * 16;
  int grow = m0 + srow;
  const f16x8* Bf = (const f16x8*)Bh;

  f32x4 acc[2][2];
  f32x4 zf = {0.f, 0.f, 0.f, 0.f};
#pragma unroll
  for (int mt = 0; mt < 2; ++mt)
#pragma unroll
    for (int nt = 0; nt < 2; ++nt) acc[mt][nt] = zf;

  for (int ks = 0; ks < 8; ++ks) {
    int k0 = ks * 32;
    __syncthreads();
    {
      float xv[16];
      if (grow < NN) {
        const __half* ap = A + (size_t)grow * HC + k0 + skq;
        __half2 hp[8];
        *(uint4*)&hp[0] = *(const uint4*)ap;
        *(uint4*)&hp[4] = *(const uint4*)(ap + 8);
#pragma unroll
        for (int j = 0; j < 8; ++j) {
          float2 f = __half22float2(hp[j]);
          xv[2 * j] = f.x;
          xv[2 * j + 1] = f.y;
        }
      } else {
#pragma unroll
        for (int j = 0; j < 16; ++j) xv[j] = 0.f;
      }
      f16x8 v0, v1;
#pragma unroll
      for (int j = 0; j < 8; ++j) {
        float a_ = abL[k0 + skq + j], b_ = abL[256 + k0 + skq + j];
        v0[j] = (_Float16)fmaxf(fmaf(xv[j], a_, b_), 0.f);
      }
#pragma unroll
      for (int j = 0; j < 8; ++j) {
        float a_ = abL[k0 + skq + 8 + j], b_ = abL[256 + k0 + skq + 8 + j];
        v1[j] = (_Float16)fmaxf(fmaf(xv[8 + j], a_, b_), 0.f);
      }
      *(f16x8*)&As[srow * 40 + skq] = v0;
      *(f16x8*)&As[srow * 40 + skq + 8] = v1;
    }
    __syncthreads();
    f16x8 af[2], bf[2];
    int lr = wv * 32 + (lane & 15);
    int kk = (lane >> 4) * 8;
#pragma unroll
    for (int mt = 0; mt < 2; ++mt)
      af[mt] = *(const f16x8*)&As[(lr + mt * 16) * 40 + kk];
#pragma unroll
    for (int nt = 0; nt < 2; ++nt)
      bf[nt] = Bf[(size_t)(nt * 8 + ks) * 64 + lane];
#pragma unroll
    for (int mt = 0; mt < 2; ++mt)
#pragma unroll
      for (int nt = 0; nt < 2; ++nt)
        acc[mt][nt] = __builtin_amdgcn_mfma_f32_16x16x32_f16(af[mt], bf[nt], acc[mt][nt], 0, 0, 0);
  }

  float as3v[2], ad3v[2];
#pragma unroll
  for (int nt = 0; nt < 2; ++nt) {
    as3v[nt] = asf[nt * 16 + (lane & 15)];
    ad3v[nt] = adf[nt * 16 + (lane & 15)];
  }
#pragma unroll
  for (int mt = 0; mt < 2; ++mt) {
    int rowb = m0 + wv * 32 + mt * 16 + (lane >> 4) * 4;
#pragma unroll
    for (int r = 0; r < 4; ++r) {
      int row = rowb + r;
      float pe = 0.f, pd = 0.f;
#pragma unroll
      for (int nt = 0; nt < 2; ++nt) {
        int col = nt * 16 + (lane & 15);
        if (row < NN) h3[(size_t)row * OUTD + col] = __float2half(acc[mt][nt][r]);
        pe = fmaf(acc[mt][nt][r], as3v[nt], pe);
        pd = fmaf(acc[mt][nt][r], ad3v[nt], pd);
      }
      pe = qred16(pe);
      pd = qred16(pd);
      if ((lane & 15) == 0 && row < NN) {
        es3[row] = pe;
        ed3[row] = pd;
      }
    }
  }
}

// ------- GAT aggregate, heads=1, ch=32, fp16 h3: wave-per-node, 2 edges/iter -------
__global__ __launch_bounds__(256) void gat_agg32(
    const __half* __restrict__ h3, const float* __restrict__ es3,
    const float* __restrict__ ed3, const int* __restrict__ offs,
    const int* __restrict__ elist, const float* __restrict__ b3,
    float* __restrict__ emb) {
  int t = threadIdx.x, wv = t >> 6, lane = t & 63;
  int eo = lane >> 5, c = lane & 31;
  float bv = b3[c];
  int i = blockIdx.x * 4 + wv;
  if (i >= NN) return;
  int base = offs[i], end = offs[i + 1];
  float edv = ed3[i];
  float denom = 0.f, acc = 0.f;
#pragma unroll 2
  for (int e = base + eo; e < end; e += 2) {
    int src = elist[e];
    float ex = __expf(lrelu(es3[src] + edv));
    denom += ex;
    acc = fmaf(ex, __half2float(h3[(size_t)src * OUTD + c]), acc);
  }
  denom += __shfl_xor(denom, 32);
  acc += __shfl_xor(acc, 32);
  if (eo == 0) emb[(size_t)i * OUTD + c] = acc / (denom + 1e-16f) + bv;
}

// ---------------- MLP head ----------------
__global__ void c1_k(const float* __restrict__ emb, const int* __restrict__ srcn,
                     const float* __restrict__ Wm1, const float* __restrict__ bm1,
                     float* __restrict__ c1) {
  int l = threadIdx.x;  // 64 threads
  int sn = srcn[0];
  float a = bm1[l];
  for (int k = 0; k < 32; ++k) a = fmaf(emb[(size_t)sn * OUTD + k], Wm1[k * 64 + l], a);
  c1[l] = a;
}

__global__ __launch_bounds__(256) void mlp_k(
    const float* __restrict__ emb, const float* __restrict__ c1,
    const float* __restrict__ Wm1, const float* __restrict__ Wm2,
    const float* __restrict__ bm2, const float* __restrict__ Wm3,
    const float* __restrict__ bm3, float* __restrict__ outp) {
  __shared__ float WL1s[32][64];
  __shared__ float WL2s[64][32];
  __shared__ float W3s[32];
  __shared__ float c1s[64];
  int t = threadIdx.x;
  for (int q = t; q < 2048; q += 256) WL1s[q >> 6][q & 63] = Wm1[(32 + (q >> 6)) * 64 + (q & 63)];
  for (int q = t; q < 2048; q += 256) WL2s[q >> 5][q & 31] = Wm2[q];
  if (t < 32) W3s[t] = Wm3[t];
  if (t < 64) c1s[t] = c1[t];
  __syncthreads();
  int wv = t >> 6, lane = t & 63;
  int p = lane >> 5, c = lane & 31;
  float bm2v = bm2[c];
  float bm3v = bm3[0];
  for (int node = blockIdx.x * 4 + wv; node < NN; node += gridDim.x * 4) {
    float zv = (lane < 32) ? emb[(size_t)node * OUTD + lane] : 0.f;
    float a1 = c1s[lane];
#pragma unroll
    for (int k = 0; k < 32; ++k) a1 = fmaf(__shfl(zv, k), WL1s[k][lane], a1);
    float u1 = fmaxf(a1, 0.f);
    float a2 = 0.f;
#pragma unroll
    for (int j = 0; j < 32; ++j) a2 = fmaf(__shfl(u1, p * 32 + j), WL2s[p * 32 + j][c], a2);
    a2 += __shfl_xor(a2, 32);
    float v = 0.f;
    if (lane < 32) {
      float u2 = fmaxf(a2 + bm2v, 0.f);
      v = u2 * W3s[c];
    }
    v = wred_sum(v);
    if (lane == 0) outp[node] = 1.f / (1.f + __expf(-(v + bm3v)));
  }
}

// ---------------- host launcher ----------------
extern "C" void kernel_launch(void* const* d_in, const int* in_sizes, int n_in,
                              void* d_out, int out_size, void* d_ws, size_t ws_size,
                              hipStream_t stream) {
  const float* x   = (const float*)d_in[0];
  const int* eidx  = (const int*)d_in[1];
  const int* srcn  = (const int*)d_in[2];
  const float* W1  = (const float*)d_in[3];
  const float* as1 = (const float*)d_in[4];
  const float* ad1 = (const float*)d_in[5];
  const float* b1  = (const float*)d_in[6];
  const float* g1  = (const float*)d_in[7];
  const float* be1 = (const float*)d_in[8];
  const float* W2  = (const float*)d_in[9];
  const float* as2 = (const float*)d_in[10];
  const float* ad2 = (const float*)d_in[11];
  const float* b2  = (const float*)d_in[12];
  const float* g2  = (const float*)d_in[13];
  const float* be2 = (const float*)d_in[14];
  const float* W3  = (const float*)d_in[15];
  const float* as3 = (const float*)d_in[16];
  const float* ad3 = (const float*)d_in[17];
  const float* b3  = (const float*)d_in[18];
  const float* Wm1 = (const float*)d_in[19];
  const float* bm1 = (const float*)d_in[20];
  const float* Wm2 = (const float*)d_in[21];
  const float* bm2 = (const float*)d_in[22];
  const float* Wm3 = (const float*)d_in[23];
  const float* bm3 = (const float*)d_in[24];
  float* outp = (float*)d_out;

  // workspace carve (256B-aligned chunks)
  char* wp = (char*)d_ws;
  auto carve = [&](size_t bytes) {
    void* p = (void*)wp;
    wp += (bytes + 255) & ~(size_t)255;
    return p;
  };
  __half* aggB  = (__half*)carve((size_t)NN * HC * 2);   // fp16 agg output
  __half* hbuf  = (__half*)carve((size_t)NN * HC * 2);   // fp16 h
  __half* h3h   = (__half*)carve((size_t)NN * OUTD * 2); // fp16 h3
  float* emb    = (float*)carve((size_t)NN * OUTD * 4);
  float* es     = (float*)carve((size_t)NN * HEADS * 4);
  float* ed     = (float*)carve((size_t)NN * HEADS * 4);
  float* es3    = (float*)carve((size_t)NN * 4);
  float* ed3    = (float*)carve((size_t)NN * 4);
  float* bnsums = (float*)carve(2 * HC * 4);
  float* bnab   = (float*)carve(2 * HC * 4);
  float* c1     = (float*)carve(64 * 4);
  __half* Bh    = (__half*)carve((size_t)HC * HC * 2);   // swizzled W2 fp16
  __half* Bh3   = (__half*)carve((size_t)HC * OUTD * 2); // swizzled W3 fp16
  int* offs     = (int*)carve((NN + 4) * 4);
  int* cursor   = (int*)carve(NN * 4);
  int* elist    = (int*)carve((size_t)ETOT * 4);
  int* part     = (int*)carve(NN * 4);
  int* bsum     = (int*)carve(256 * 4);
  int* bscan    = (int*)carve(256 * 4);

  const int TB = 256;
  const int gE = (ETOT + TB - 1) / TB;
  const int gN4 = (NN + 3) / 4;

  // ---- CSR build ----
  zero_i32<<<(NN + TB - 1) / TB, TB, 0, stream>>>(cursor, NN);
  hist_k<<<gE, TB, 0, stream>>>(eidx, cursor);
  scan1_k<<<NB1, TB, 0, stream>>>(cursor, part, bsum);
  scan2_k<<<1, TB, 0, stream>>>(bsum, bscan);
  scan3_k<<<NB1, TB, 0, stream>>>(part, bscan, offs, cursor);
  scatter_k<<<gE, TB, 0, stream>>>(eidx, cursor, elist);
  wswz_k<HC><<<HC * HC / TB, TB, 0, stream>>>(W2, Bh);
  wswz_k<OUTD><<<HC * OUTD / TB, TB, 0, stream>>>(W3, Bh3);

  // ---- layer 1 ----
  l1_h_k<<<2048, TB, 0, stream>>>(x, W1, as1, ad1, hbuf, es, ed);
  gat_agg256<<<gN4, TB, 0, stream>>>(hbuf, es, ed, offs, elist, b1, aggB);
  zero_i32<<<2, TB, 0, stream>>>((int*)bnsums, 2 * HC);
  bn_stats_k<<<(NN + 63) / 64, TB, 0, stream>>>(aggB, bnsums);
  bn_final_k<<<1, TB, 0, stream>>>(bnsums, g1, be1, bnab);

  // ---- layer 2: MFMA GEMM (BN1 affine+relu fused in; es2/ed2 fused epilogue) ----
  gemm_mfma_k<<<dim3((NN + 127) / 128, HC / 128), TB, 0, stream>>>(aggB, Bh, bnab, as2, ad2,
                                                                   hbuf, es, ed);
  gat_agg256<<<gN4, TB, 0, stream>>>(hbuf, es, ed, offs, elist, b2, aggB);
  zero_i32<<<2, TB, 0, stream>>>((int*)bnsums, 2 * HC);
  bn_stats_k<<<(NN + 63) / 64, TB, 0, stream>>>(aggB, bnsums);
  bn_final_k<<<1, TB, 0, stream>>>(bnsums, g2, be2, bnab);

  // ---- layer 3: MFMA (BN2 affine+relu fused; es3/ed3 fused epilogue) ----
  l3_mfma_k<<<(NN + 127) / 128, TB, 0, stream>>>(aggB, Bh3, bnab, as3, ad3, h3h, es3, ed3);
  gat_agg32<<<gN4, TB, 0, stream>>>(h3h, es3, ed3, offs, elist, b3, emb);

  // ---- MLP head ----
  c1_k<<<1, 64, 0, stream>>>(emb, srcn, Wm1, bm1, c1);
  mlp_k<<<512, TB, 0, stream>>>(emb, c1, Wm1, Wm2, bm2, Wm3, bm3, outp);
}